// Round 1
// baseline (3240.151 us; speedup 1.0000x reference)
//
#include <hip/hip_runtime.h>
#include <hip/hip_bf16.h>
#include <math.h>

#define BGRAPH 128
#define NPER0 1024
#define DDIM 64
#define NTOT (BGRAPH*NPER0)      // 131072
#define ETOT (NTOT*16)           // 2097152
#define KK1 820
#define KK2 656
#define KK3 525

// ---------- kernels ----------

__global__ void k_embed(const int* __restrict__ ids, const float* __restrict__ emb,
                        float* __restrict__ x) {
    int i = blockIdx.x * blockDim.x + threadIdx.x;
    if (i < NTOT * DDIM) {
        int n = i >> 6, d = i & 63;
        x[i] = emb[ids[n] * DDIM + d];
    }
}

__global__ void k_copy_edges(const int* __restrict__ ein, int* __restrict__ src,
                             int* __restrict__ dst) {
    int e = blockIdx.x * blockDim.x + threadIdx.x;
    if (e < ETOT) { src[e] = ein[e]; dst[e] = ein[ETOT + e]; }
}

// msg = relu(x @ W.T + b), W is [64][64] row-major, 4 nodes per 256-thread block
__global__ void k_dense_relu(const float* __restrict__ x, const float* __restrict__ W,
                             const float* __restrict__ bvec, float* __restrict__ out) {
    __shared__ float xs[4 * 64];
    int w = threadIdx.x >> 6, d = threadIdx.x & 63;
    int node = blockIdx.x * 4 + w;
    xs[w * 64 + d] = x[node * 64 + d];
    __syncthreads();
    float acc = bvec[d];
    const float* wr = W + d * 64;
    const float* xr = xs + w * 64;
    #pragma unroll 8
    for (int k = 0; k < 64; k++) acc = fmaf(wr[k], xr[k], acc);
    out[node * 64 + d] = fmaxf(acc, 0.f);
}

// aggr[dst] = max(aggr[dst], msg[src]) over valid edges (src>=0). one edge per wave
__global__ void k_edge_max(const int* __restrict__ src, const int* __restrict__ dst,
                           const float* __restrict__ msg, float* __restrict__ aggr) {
    int t = blockIdx.x * blockDim.x + threadIdx.x;
    int e = t >> 6, d = t & 63;
    if (e >= ETOT) return;
    int s = src[e];
    if (s < 0) return;
    float v = msg[s * 64 + d];
    atomicMax((unsigned int*)&aggr[dst[e] * 64 + d], __float_as_uint(v));
}

// out = relu(concat(aggr, x) @ U.T), U is [64][128]
__global__ void k_concat_dense_relu(const float* __restrict__ aggr, const float* __restrict__ x,
                                    const float* __restrict__ U, float* __restrict__ out) {
    __shared__ float s[4 * 128];
    int w = threadIdx.x >> 6, d = threadIdx.x & 63;
    int node = blockIdx.x * 4 + w;
    s[w * 128 + d]      = aggr[node * 64 + d];
    s[w * 128 + 64 + d] = x[node * 64 + d];
    __syncthreads();
    float acc = 0.f;
    const float* u = U + d * 128;
    const float* sr = s + w * 128;
    #pragma unroll 8
    for (int k = 0; k < 128; k++) acc = fmaf(u[k], sr[k], acc);
    out[node * 64 + d] = fmaxf(acc, 0.f);
}

__global__ void k_pnorm(const float* __restrict__ p, float* __restrict__ pn) {
    int d = threadIdx.x;
    float v = p[d] * p[d];
    for (int o = 32; o > 0; o >>= 1) v += __shfl_down(v, o);
    if (d == 0) pn[0] = sqrtf(v);
}

__global__ void k_score(const float* __restrict__ x, const float* __restrict__ p,
                        const float* __restrict__ pn, float* __restrict__ score) {
    int w = threadIdx.x >> 6, lane = threadIdx.x & 63;
    int node = blockIdx.x * 4 + w;
    float v = x[node * 64 + lane] * p[lane];
    for (int o = 32; o > 0; o >>= 1) v += __shfl_down(v, o);
    if (lane == 0) score[node] = v / pn[0];
}

// per-graph bitonic sort of 1024 (value,index) pairs, descending value / ascending index
__global__ void k_topk(const float* __restrict__ score, int nper, int k,
                       float* __restrict__ topv, int* __restrict__ topi) {
    __shared__ float sv[1024];
    __shared__ int   si[1024];
    int g = blockIdx.x;
    for (int i = threadIdx.x; i < 1024; i += blockDim.x) {
        sv[i] = (i < nper) ? score[g * nper + i] : -INFINITY;
        si[i] = i;
    }
    __syncthreads();
    for (int ksz = 2; ksz <= 1024; ksz <<= 1) {
        for (int j = ksz >> 1; j > 0; j >>= 1) {
            for (int i = threadIdx.x; i < 1024; i += blockDim.x) {
                int ixj = i ^ j;
                if (ixj > i) {
                    float va = sv[i], vb = sv[ixj];
                    int ia = si[i], ib = si[ixj];
                    bool up = ((i & ksz) == 0);
                    bool aBefore = (va > vb) || (va == vb && ia < ib);
                    if (up != aBefore) { sv[i] = vb; sv[ixj] = va; si[i] = ib; si[ixj] = ia; }
                }
            }
            __syncthreads();
        }
    }
    for (int i = threadIdx.x; i < k; i += blockDim.x) {
        topv[g * 1024 + i] = sv[i];
        topi[g * 1024 + i] = si[i];
    }
}

__global__ void k_init_inv(int* __restrict__ inv, int n) {
    int i = blockIdx.x * blockDim.x + threadIdx.x;
    if (i < n) inv[i] = -1;
}

// xnew[j] = x[perm[j]] * tanh(topv[j]); inv[perm[j]] = j. 4 rows per block
__global__ void k_gather(const float* __restrict__ x, const float* __restrict__ topv,
                         const int* __restrict__ topi, float* __restrict__ xnew,
                         int* __restrict__ inv, int nper, int k) {
    int w = threadIdx.x >> 6, d = threadIdx.x & 63;
    int j = blockIdx.x * 4 + w;
    int g = j / k, jj = j - g * k;
    int t = topi[g * 1024 + jj];
    int old = g * nper + t;
    float sc = tanhf(topv[g * 1024 + jj]);
    xnew[j * 64 + d] = x[old * 64 + d] * sc;
    if (d == 0) inv[old] = j;
}

__global__ void k_remap(int* __restrict__ src, int* __restrict__ dst,
                        const int* __restrict__ inv) {
    int e = blockIdx.x * blockDim.x + threadIdx.x;
    if (e >= ETOT) return;
    int s = src[e];
    if (s < 0) return;
    int ns = inv[s], nd = inv[dst[e]];
    if (ns >= 0 && nd >= 0) { src[e] = ns; dst[e] = nd; }
    else src[e] = -1;
}

// r[g] = [max over k rows, mean over k rows] of x[g*k .. g*k+k)
__global__ void k_readout(const float* __restrict__ x, float* __restrict__ r, int k) {
    int g = blockIdx.x, c = threadIdx.x;   // 128 threads
    int d = c & 63;
    const float* base = x + (size_t)g * k * 64 + d;
    if (c < 64) {
        float m = -INFINITY;
        for (int j = 0; j < k; j++) m = fmaxf(m, base[j * 64]);
        r[g * 128 + c] = m;
    } else {
        float s = 0.f;
        for (int j = 0; j < k; j++) s += base[j * 64];
        r[g * 128 + c] = s / (float)k;
    }
}

__global__ void k_mlp(const float* __restrict__ r1, const float* __restrict__ r2,
                      const float* __restrict__ r3,
                      const float* __restrict__ l1W, const float* __restrict__ l1b,
                      const float* __restrict__ l2W, const float* __restrict__ l2b,
                      const float* __restrict__ l3W, const float* __restrict__ l3b,
                      float* __restrict__ out) {
    __shared__ float h[128], h1[64], h2[64];
    int g = blockIdx.x, d = threadIdx.x;   // 64 threads
    h[d]      = r1[g*128 + d]      + r2[g*128 + d]      + r3[g*128 + d];
    h[d + 64] = r1[g*128 + 64 + d] + r2[g*128 + 64 + d] + r3[g*128 + 64 + d];
    __syncthreads();
    float a = l1b[d];
    for (int k = 0; k < 128; k++) a = fmaf(l1W[d*128 + k], h[k], a);
    h1[d] = fmaxf(a, 0.f);
    __syncthreads();
    a = l2b[d];
    for (int k = 0; k < 64; k++) a = fmaf(l2W[d*64 + k], h1[k], a);
    h2[d] = fmaxf(a, 0.f);
    __syncthreads();
    a = l3b[d];
    for (int k = 0; k < 64; k++) a = fmaf(l3W[d*64 + k], h2[k], a);
    out[g*64 + d] = 1.f / (1.f + expf(-a));
}

__global__ void k_batch(float* __restrict__ out) {
    int i = blockIdx.x * blockDim.x + threadIdx.x;
    if (i < BGRAPH * KK3) out[i] = (float)(i / KK3);
}

// ---------- launch ----------

extern "C" void kernel_launch(void* const* d_in, const int* in_sizes, int n_in,
                              void* d_out, int out_size, void* d_ws, size_t ws_size,
                              hipStream_t stream) {
    const int*   x_ids = (const int*)  d_in[0];
    const int*   eidx  = (const int*)  d_in[1];
    const float* emb   = (const float*)d_in[2];
    const float* Wl[3] = {(const float*)d_in[3],  (const float*)d_in[7],  (const float*)d_in[11]};
    const float* bl[3] = {(const float*)d_in[4],  (const float*)d_in[8],  (const float*)d_in[12]};
    const float* Ul[3] = {(const float*)d_in[5],  (const float*)d_in[9],  (const float*)d_in[13]};
    const float* pl[3] = {(const float*)d_in[6],  (const float*)d_in[10], (const float*)d_in[14]};
    const float* l1W = (const float*)d_in[15]; const float* l1b = (const float*)d_in[16];
    const float* l2W = (const float*)d_in[17]; const float* l2b = (const float*)d_in[18];
    const float* l3W = (const float*)d_in[19]; const float* l3b = (const float*)d_in[20];

    float* ws   = (float*)d_ws;
    float* xA   = ws;
    float* xB   = xA + (size_t)NTOT * DDIM;
    float* xC   = xB + (size_t)NTOT * DDIM;
    float* score= xC + (size_t)NTOT * DDIM;
    float* topv = score + NTOT;
    float* r1   = topv + BGRAPH * 1024;
    float* r2   = r1 + BGRAPH * 128;
    float* r3   = r2 + BGRAPH * 128;
    float* pn   = r3 + BGRAPH * 128;
    int*   src  = (int*)(pn + 4);
    int*   dst  = src + ETOT;
    int*   inv  = dst + ETOT;
    int*   topi = inv + NTOT;

    float* rr[3] = {r1, r2, r3};
    const int nperl[3] = {NPER0, KK1, KK2};
    const int kl[3]    = {KK1, KK2, KK3};

    k_embed<<<(NTOT * DDIM + 255) / 256, 256, 0, stream>>>(x_ids, emb, xA);
    k_copy_edges<<<(ETOT + 255) / 256, 256, 0, stream>>>(eidx, src, dst);

    float *x = xA, *m = xB, *a = xC;
    int n = NTOT;
    for (int l = 0; l < 3; l++) {
        // SAGE
        k_dense_relu<<<n / 4, 256, 0, stream>>>(x, Wl[l], bl[l], m);
        hipMemcpyAsync(a, m, (size_t)n * 64 * sizeof(float), hipMemcpyDeviceToDevice, stream);
        k_edge_max<<<ETOT / 4, 256, 0, stream>>>(src, dst, m, a);
        k_concat_dense_relu<<<n / 4, 256, 0, stream>>>(a, x, Ul[l], m);  // y -> m
        // TopK
        k_pnorm<<<1, 64, 0, stream>>>(pl[l], pn);
        k_score<<<n / 4, 256, 0, stream>>>(m, pl[l], pn, score);
        k_init_inv<<<(n + 255) / 256, 256, 0, stream>>>(inv, n);
        k_topk<<<BGRAPH, 256, 0, stream>>>(score, nperl[l], kl[l], topv, topi);
        int nn = BGRAPH * kl[l];
        k_gather<<<nn / 4, 256, 0, stream>>>(m, topv, topi, a, inv, nperl[l], kl[l]);
        if (l < 2) k_remap<<<(ETOT + 255) / 256, 256, 0, stream>>>(src, dst, inv);
        k_readout<<<BGRAPH, 128, 0, stream>>>(a, rr[l], kl[l]);
        // rotate buffers: new x in a
        float* t = x; x = a; a = m; m = t;
        n = nn;
    }

    k_mlp<<<BGRAPH, 64, 0, stream>>>(r1, r2, r3, l1W, l1b, l2W, l2b, l3W, l3b, (float*)d_out);
    k_batch<<<(BGRAPH * KK3 + 255) / 256, 256, 0, stream>>>((float*)d_out + BGRAPH * DDIM);
}

// Round 2
// 2020.751 us; speedup vs baseline: 1.6034x; 1.6034x over previous
//
#include <hip/hip_runtime.h>
#include <hip/hip_bf16.h>
#include <math.h>

#define BGRAPH 128
#define NPER0 1024
#define DDIM 64
#define NTOT (BGRAPH*NPER0)      // 131072
#define ETOT (NTOT*16)           // 2097152
#define EPG  (ETOT/BGRAPH)       // 16384 edges per graph
#define KK1 820
#define KK2 656
#define KK3 525

// ---------- kernels ----------

__global__ void k_embed(const int* __restrict__ ids, const float* __restrict__ emb,
                        float4* __restrict__ x) {
    int i = blockIdx.x * blockDim.x + threadIdx.x;   // one float4 per thread
    if (i < NTOT * 16) {
        int n = i >> 4, d4 = i & 15;
        x[i] = ((const float4*)emb)[ids[n] * 16 + d4];
    }
}

__global__ void k_copy_edges(const int4* __restrict__ ein, int4* __restrict__ src,
                             int4* __restrict__ dst) {
    int e = blockIdx.x * blockDim.x + threadIdx.x;
    if (e < ETOT / 4) { src[e] = ein[e]; dst[e] = ein[ETOT / 4 + e]; }
}

// msg = relu(x @ W.T + b). One node per thread, weights via uniform (SGPR) loads,
// outputs staged in LDS for coalesced write. Block = 64 threads = 64 nodes.
__global__ __launch_bounds__(64) void k_dense64(const float* __restrict__ x,
                                                const float* __restrict__ W,
                                                const float* __restrict__ b,
                                                float* __restrict__ out) {
    __shared__ float tile[64 * 65];
    int lane = threadIdx.x;
    int node0 = blockIdx.x * 64;
    int node = node0 + lane;
    float xr[64];
    const float4* xp = (const float4*)(x + (size_t)node * 64);
    #pragma unroll
    for (int i = 0; i < 16; i++) {
        float4 v = xp[i];
        xr[4*i] = v.x; xr[4*i+1] = v.y; xr[4*i+2] = v.z; xr[4*i+3] = v.w;
    }
    for (int d = 0; d < 64; d += 2) {
        float a0 = b[d], a1 = b[d + 1];
        #pragma unroll
        for (int k = 0; k < 64; k++) {
            a0 = fmaf(W[d * 64 + k],       xr[k], a0);
            a1 = fmaf(W[(d + 1) * 64 + k], xr[k], a1);
        }
        tile[lane * 65 + d]     = fmaxf(a0, 0.f);
        tile[lane * 65 + d + 1] = fmaxf(a1, 0.f);
    }
    __syncthreads();
    #pragma unroll 4
    for (int j = 0; j < 64; j++)
        out[(size_t)(node0 + j) * 64 + lane] = tile[j * 65 + lane];
}

// h = relu(concat(aggr,x) @ U.T); also score = (h @ p)/||p|| fused.
__global__ __launch_bounds__(64) void k_dense128cat(const float* __restrict__ aggr,
                                                    const float* __restrict__ x,
                                                    const float* __restrict__ U,
                                                    const float* __restrict__ p,
                                                    const float* __restrict__ pn,
                                                    float* __restrict__ out,
                                                    float* __restrict__ score) {
    __shared__ float tile[64 * 65];
    int lane = threadIdx.x;
    int node0 = blockIdx.x * 64;
    int node = node0 + lane;
    float xr[128];
    const float4* ap = (const float4*)(aggr + (size_t)node * 64);
    const float4* xp = (const float4*)(x    + (size_t)node * 64);
    #pragma unroll
    for (int i = 0; i < 16; i++) {
        float4 v = ap[i];
        xr[4*i] = v.x; xr[4*i+1] = v.y; xr[4*i+2] = v.z; xr[4*i+3] = v.w;
    }
    #pragma unroll
    for (int i = 0; i < 16; i++) {
        float4 v = xp[i];
        xr[64+4*i] = v.x; xr[64+4*i+1] = v.y; xr[64+4*i+2] = v.z; xr[64+4*i+3] = v.w;
    }
    float sacc = 0.f;
    for (int d = 0; d < 64; d += 2) {
        float a0 = 0.f, a1 = 0.f;
        #pragma unroll
        for (int k = 0; k < 128; k++) {
            a0 = fmaf(U[d * 128 + k],       xr[k], a0);
            a1 = fmaf(U[(d + 1) * 128 + k], xr[k], a1);
        }
        a0 = fmaxf(a0, 0.f); a1 = fmaxf(a1, 0.f);
        sacc = fmaf(a0, p[d], sacc);
        sacc = fmaf(a1, p[d + 1], sacc);
        tile[lane * 65 + d]     = a0;
        tile[lane * 65 + d + 1] = a1;
    }
    score[node] = sacc / pn[0];
    __syncthreads();
    #pragma unroll 4
    for (int j = 0; j < 64; j++)
        out[(size_t)(node0 + j) * 64 + lane] = tile[j * 65 + lane];
}

// Per-graph LDS max-aggregation over a 16-dim quarter. aggr init'd from msg
// (covers self-loop + isolated nodes). XOR-swizzled [node][16] tile, <=64KB.
__global__ __launch_bounds__(256) void k_edge_max(const int* __restrict__ src,
                                                  const int* __restrict__ dst,
                                                  const float* __restrict__ msg,
                                                  float* __restrict__ aggr,
                                                  int nper) {
    extern __shared__ unsigned smax[];   // [nper][16], xor-swizzled
    int g = blockIdx.x, q = blockIdx.y;
    int t = threadIdx.x;
    int d = t & 15, es = t >> 4;         // 16 dims x 16 edges per iteration
    int nodebase = g * nper;
    for (int i = t; i < nper * 16; i += 256) {
        int node = i >> 4, dd = i & 15;
        float v = msg[(size_t)(nodebase + node) * 64 + q * 16 + dd];
        smax[(node << 4) | (dd ^ (node & 15))] = __float_as_uint(v);
    }
    __syncthreads();
    int ebase = g * EPG;
    for (int base = 0; base < EPG; base += 16) {
        int e = ebase + base + es;
        int s = src[e];
        if (s >= 0) {
            float v = msg[(size_t)s * 64 + q * 16 + d];
            int ln = dst[e] - nodebase;
            atomicMax(&smax[(ln << 4) | (d ^ (ln & 15))], __float_as_uint(v));
        }
    }
    __syncthreads();
    for (int i = t; i < nper * 16; i += 256) {
        int node = i >> 4, dd = i & 15;
        aggr[(size_t)(nodebase + node) * 64 + q * 16 + dd] =
            __uint_as_float(smax[(node << 4) | (dd ^ (node & 15))]);
    }
}

__global__ void k_pnorm(const float* __restrict__ p, float* __restrict__ pn) {
    int d = threadIdx.x;
    float v = p[d] * p[d];
    for (int o = 32; o > 0; o >>= 1) v += __shfl_down(v, o);
    if (d == 0) pn[0] = sqrtf(v);
}

// per-graph bitonic sort of 1024 (value,index) pairs, descending value / ascending index
__global__ void k_topk(const float* __restrict__ score, int nper, int k,
                       float* __restrict__ topv, int* __restrict__ topi) {
    __shared__ float sv[1024];
    __shared__ int   si[1024];
    int g = blockIdx.x;
    for (int i = threadIdx.x; i < 1024; i += blockDim.x) {
        sv[i] = (i < nper) ? score[g * nper + i] : -INFINITY;
        si[i] = i;
    }
    __syncthreads();
    for (int ksz = 2; ksz <= 1024; ksz <<= 1) {
        for (int j = ksz >> 1; j > 0; j >>= 1) {
            for (int i = threadIdx.x; i < 1024; i += blockDim.x) {
                int ixj = i ^ j;
                if (ixj > i) {
                    float va = sv[i], vb = sv[ixj];
                    int ia = si[i], ib = si[ixj];
                    bool up = ((i & ksz) == 0);
                    bool aBefore = (va > vb) || (va == vb && ia < ib);
                    if (up != aBefore) { sv[i] = vb; sv[ixj] = va; si[i] = ib; si[ixj] = ia; }
                }
            }
            __syncthreads();
        }
    }
    for (int i = threadIdx.x; i < k; i += blockDim.x) {
        topv[g * 1024 + i] = sv[i];
        topi[g * 1024 + i] = si[i];
    }
}

__global__ void k_init_inv(int* __restrict__ inv, int n) {
    int i = blockIdx.x * blockDim.x + threadIdx.x;
    if (i < n) inv[i] = -1;
}

// xnew[j] = x[perm[j]] * tanh(topv[j]); inv[perm[j]] = j. 4 rows per block
__global__ void k_gather(const float* __restrict__ x, const float* __restrict__ topv,
                         const int* __restrict__ topi, float* __restrict__ xnew,
                         int* __restrict__ inv, int nper, int k) {
    int w = threadIdx.x >> 6, d = threadIdx.x & 63;
    int j = blockIdx.x * 4 + w;
    int g = j / k, jj = j - g * k;
    int t = topi[g * 1024 + jj];
    int old = g * nper + t;
    float sc = tanhf(topv[g * 1024 + jj]);
    xnew[j * 64 + d] = x[old * 64 + d] * sc;
    if (d == 0) inv[old] = j;
}

__global__ void k_remap(int* __restrict__ src, int* __restrict__ dst,
                        const int* __restrict__ inv) {
    int e = blockIdx.x * blockDim.x + threadIdx.x;
    if (e >= ETOT) return;
    int s = src[e];
    if (s < 0) return;
    int ns = inv[s], nd = inv[dst[e]];
    if (ns >= 0 && nd >= 0) { src[e] = ns; dst[e] = nd; }
    else src[e] = -1;
}

// r[g] = [max over k rows, mean over k rows]; 4-way split over rows
__global__ __launch_bounds__(256) void k_readout(const float* __restrict__ x,
                                                 float* __restrict__ r, int k) {
    __shared__ float smx[4][64], ssm[4][64];
    int g = blockIdx.x;
    int d = threadIdx.x & 63, c = threadIdx.x >> 6;
    float m = -INFINITY, s = 0.f;
    for (int j = c; j < k; j += 4) {
        float v = x[((size_t)g * k + j) * 64 + d];
        m = fmaxf(m, v); s += v;
    }
    smx[c][d] = m; ssm[c][d] = s;
    __syncthreads();
    if (c == 0) {
        m = fmaxf(fmaxf(smx[0][d], smx[1][d]), fmaxf(smx[2][d], smx[3][d]));
        s = ssm[0][d] + ssm[1][d] + ssm[2][d] + ssm[3][d];
        r[g * 128 + d] = m;
        r[g * 128 + 64 + d] = s / (float)k;
    }
}

__global__ void k_mlp(const float* __restrict__ r1, const float* __restrict__ r2,
                      const float* __restrict__ r3,
                      const float* __restrict__ l1W, const float* __restrict__ l1b,
                      const float* __restrict__ l2W, const float* __restrict__ l2b,
                      const float* __restrict__ l3W, const float* __restrict__ l3b,
                      float* __restrict__ out) {
    __shared__ float h[128], h1[64], h2[64];
    int g = blockIdx.x, d = threadIdx.x;   // 64 threads
    h[d]      = r1[g*128 + d]      + r2[g*128 + d]      + r3[g*128 + d];
    h[d + 64] = r1[g*128 + 64 + d] + r2[g*128 + 64 + d] + r3[g*128 + 64 + d];
    __syncthreads();
    float a = l1b[d];
    for (int k = 0; k < 128; k++) a = fmaf(l1W[d*128 + k], h[k], a);
    h1[d] = fmaxf(a, 0.f);
    __syncthreads();
    a = l2b[d];
    for (int k = 0; k < 64; k++) a = fmaf(l2W[d*64 + k], h1[k], a);
    h2[d] = fmaxf(a, 0.f);
    __syncthreads();
    a = l3b[d];
    for (int k = 0; k < 64; k++) a = fmaf(l3W[d*64 + k], h2[k], a);
    out[g*64 + d] = 1.f / (1.f + expf(-a));
}

__global__ void k_batch(float* __restrict__ out) {
    int i = blockIdx.x * blockDim.x + threadIdx.x;
    if (i < BGRAPH * KK3) out[i] = (float)(i / KK3);
}

// ---------- launch ----------

extern "C" void kernel_launch(void* const* d_in, const int* in_sizes, int n_in,
                              void* d_out, int out_size, void* d_ws, size_t ws_size,
                              hipStream_t stream) {
    const int*   x_ids = (const int*)  d_in[0];
    const int*   eidx  = (const int*)  d_in[1];
    const float* emb   = (const float*)d_in[2];
    const float* Wl[3] = {(const float*)d_in[3],  (const float*)d_in[7],  (const float*)d_in[11]};
    const float* bl[3] = {(const float*)d_in[4],  (const float*)d_in[8],  (const float*)d_in[12]};
    const float* Ul[3] = {(const float*)d_in[5],  (const float*)d_in[9],  (const float*)d_in[13]};
    const float* pl[3] = {(const float*)d_in[6],  (const float*)d_in[10], (const float*)d_in[14]};
    const float* l1W = (const float*)d_in[15]; const float* l1b = (const float*)d_in[16];
    const float* l2W = (const float*)d_in[17]; const float* l2b = (const float*)d_in[18];
    const float* l3W = (const float*)d_in[19]; const float* l3b = (const float*)d_in[20];

    float* ws   = (float*)d_ws;
    float* xA   = ws;
    float* xB   = xA + (size_t)NTOT * DDIM;
    float* xC   = xB + (size_t)NTOT * DDIM;
    float* score= xC + (size_t)NTOT * DDIM;
    float* topv = score + NTOT;
    float* r1   = topv + BGRAPH * 1024;
    float* r2   = r1 + BGRAPH * 128;
    float* r3   = r2 + BGRAPH * 128;
    float* pn   = r3 + BGRAPH * 128;
    int*   src  = (int*)(pn + 4);
    int*   dst  = src + ETOT;
    int*   inv  = dst + ETOT;
    int*   topi = inv + NTOT;

    float* rr[3] = {r1, r2, r3};
    const int nperl[3] = {NPER0, KK1, KK2};
    const int kl[3]    = {KK1, KK2, KK3};

    k_embed<<<(NTOT * 16 + 255) / 256, 256, 0, stream>>>(x_ids, emb, (float4*)xA);
    k_copy_edges<<<(ETOT / 4 + 255) / 256, 256, 0, stream>>>((const int4*)eidx, (int4*)src, (int4*)dst);

    float *x = xA, *m = xB, *a = xC;
    int n = NTOT;
    for (int l = 0; l < 3; l++) {
        int nper = nperl[l], k = kl[l];
        // SAGE
        k_dense64<<<n / 64, 64, 0, stream>>>(x, Wl[l], bl[l], m);
        k_edge_max<<<dim3(BGRAPH, 4), 256, nper * 16 * sizeof(float), stream>>>(src, dst, m, a, nper);
        k_pnorm<<<1, 64, 0, stream>>>(pl[l], pn);
        k_dense128cat<<<n / 64, 64, 0, stream>>>(a, x, Ul[l], pl[l], pn, m, score);
        // TopK
        k_init_inv<<<(n + 255) / 256, 256, 0, stream>>>(inv, n);
        k_topk<<<BGRAPH, 256, 0, stream>>>(score, nper, k, topv, topi);
        int nn = BGRAPH * k;
        k_gather<<<nn / 4, 256, 0, stream>>>(m, topv, topi, a, inv, nper, k);
        if (l < 2) k_remap<<<(ETOT + 255) / 256, 256, 0, stream>>>(src, dst, inv);
        k_readout<<<BGRAPH, 256, 0, stream>>>(a, rr[l], k);
        // rotate buffers: new x in a
        float* t = x; x = a; a = m; m = t;
        n = nn;
    }

    k_mlp<<<BGRAPH, 64, 0, stream>>>(r1, r2, r3, l1W, l1b, l2W, l2b, l3W, l3b, (float*)d_out);
    k_batch<<<(BGRAPH * KK3 + 255) / 256, 256, 0, stream>>>((float*)d_out + BGRAPH * DDIM);
}

// Round 3
// 1310.021 us; speedup vs baseline: 2.4734x; 1.5425x over previous
//
#include <hip/hip_runtime.h>
#include <hip/hip_bf16.h>
#include <math.h>

#define BGRAPH 128
#define NPER0 1024
#define DDIM 64
#define NTOT (BGRAPH*NPER0)      // 131072
#define ETOT (NTOT*16)           // 2097152
#define EPG  (ETOT/BGRAPH)       // 16384 edges per graph
#define KK1 820
#define KK2 656
#define KK3 525

// ---------- kernels ----------

__global__ void k_embed(const int* __restrict__ ids, const float* __restrict__ emb,
                        float4* __restrict__ x) {
    int i = blockIdx.x * blockDim.x + threadIdx.x;   // one float4 per thread
    if (i < NTOT * 16) {
        int n = i >> 4, d4 = i & 15;
        x[i] = ((const float4*)emb)[ids[n] * 16 + d4];
    }
}

__global__ void k_copy_edges(const int4* __restrict__ ein, int4* __restrict__ src,
                             int4* __restrict__ dst) {
    int e = blockIdx.x * blockDim.x + threadIdx.x;
    if (e < ETOT / 4) { src[e] = ein[e]; dst[e] = ein[ETOT / 4 + e]; }
}

// msg = relu(x @ W.T + b). One node per thread, weights via uniform (SGPR) loads,
// outputs staged in LDS for coalesced write. Block = 64 threads = 64 nodes.
__global__ __launch_bounds__(64) void k_dense64(const float* __restrict__ x,
                                                const float* __restrict__ W,
                                                const float* __restrict__ b,
                                                float* __restrict__ out) {
    __shared__ float tile[64 * 65];
    int lane = threadIdx.x;
    int node0 = blockIdx.x * 64;
    int node = node0 + lane;
    float xr[64];
    const float4* xp = (const float4*)(x + (size_t)node * 64);
    #pragma unroll
    for (int i = 0; i < 16; i++) {
        float4 v = xp[i];
        xr[4*i] = v.x; xr[4*i+1] = v.y; xr[4*i+2] = v.z; xr[4*i+3] = v.w;
    }
    for (int d = 0; d < 64; d += 2) {
        float a0 = b[d], a1 = b[d + 1];
        #pragma unroll
        for (int k = 0; k < 64; k++) {
            a0 = fmaf(W[d * 64 + k],       xr[k], a0);
            a1 = fmaf(W[(d + 1) * 64 + k], xr[k], a1);
        }
        tile[lane * 65 + d]     = fmaxf(a0, 0.f);
        tile[lane * 65 + d + 1] = fmaxf(a1, 0.f);
    }
    __syncthreads();
    #pragma unroll 4
    for (int j = 0; j < 64; j++)
        out[(size_t)(node0 + j) * 64 + lane] = tile[j * 65 + lane];
}

// h = relu(concat(aggr,x) @ U.T); also score = (h @ p)/||p|| fused.
__global__ __launch_bounds__(64) void k_dense128cat(const float* __restrict__ aggr,
                                                    const float* __restrict__ x,
                                                    const float* __restrict__ U,
                                                    const float* __restrict__ p,
                                                    const float* __restrict__ pn,
                                                    float* __restrict__ out,
                                                    float* __restrict__ score) {
    __shared__ float tile[64 * 65];
    int lane = threadIdx.x;
    int node0 = blockIdx.x * 64;
    int node = node0 + lane;
    float xr[128];
    const float4* ap = (const float4*)(aggr + (size_t)node * 64);
    const float4* xp = (const float4*)(x    + (size_t)node * 64);
    #pragma unroll
    for (int i = 0; i < 16; i++) {
        float4 v = ap[i];
        xr[4*i] = v.x; xr[4*i+1] = v.y; xr[4*i+2] = v.z; xr[4*i+3] = v.w;
    }
    #pragma unroll
    for (int i = 0; i < 16; i++) {
        float4 v = xp[i];
        xr[64+4*i] = v.x; xr[64+4*i+1] = v.y; xr[64+4*i+2] = v.z; xr[64+4*i+3] = v.w;
    }
    float sacc = 0.f;
    for (int d = 0; d < 64; d += 2) {
        float a0 = 0.f, a1 = 0.f;
        #pragma unroll
        for (int k = 0; k < 128; k++) {
            a0 = fmaf(U[d * 128 + k],       xr[k], a0);
            a1 = fmaf(U[(d + 1) * 128 + k], xr[k], a1);
        }
        a0 = fmaxf(a0, 0.f); a1 = fmaxf(a1, 0.f);
        sacc = fmaf(a0, p[d], sacc);
        sacc = fmaf(a1, p[d + 1], sacc);
        tile[lane * 65 + d]     = a0;
        tile[lane * 65 + d + 1] = a1;
    }
    score[node] = sacc / pn[0];
    __syncthreads();
    #pragma unroll 4
    for (int j = 0; j < 64; j++)
        out[(size_t)(node0 + j) * 64 + lane] = tile[j * 65 + lane];
}

// Per-graph LDS max-aggregation over a 16-dim quarter. aggr init'd from msg
// (covers self-loop + isolated nodes). 1024 threads: 64 edges x 16 dims / iter.
__global__ __launch_bounds__(1024) void k_edge_max(const int* __restrict__ src,
                                                   const int* __restrict__ dst,
                                                   const float* __restrict__ msg,
                                                   float* __restrict__ aggr,
                                                   int nper) {
    extern __shared__ unsigned smax[];   // [nper][16], xor-swizzled
    int g = blockIdx.x, q = blockIdx.y;
    int t = threadIdx.x;
    int d = t & 15, es = t >> 4;         // 16 dims x 64 edges per iteration
    int nodebase = g * nper;
    for (int i = t; i < nper * 16; i += 1024) {
        int node = i >> 4, dd = i & 15;
        float v = msg[(size_t)(nodebase + node) * 64 + q * 16 + dd];
        smax[(node << 4) | (dd ^ (node & 15))] = __float_as_uint(v);
    }
    __syncthreads();
    int ebase = g * EPG;
    for (int base = 0; base < EPG; base += 64) {
        int e = ebase + base + es;
        int s = src[e];
        if (s >= 0) {
            float v = msg[(size_t)s * 64 + q * 16 + d];
            int ln = dst[e] - nodebase;
            atomicMax(&smax[(ln << 4) | (d ^ (ln & 15))], __float_as_uint(v));
        }
    }
    __syncthreads();
    for (int i = t; i < nper * 16; i += 1024) {
        int node = i >> 4, dd = i & 15;
        aggr[(size_t)(nodebase + node) * 64 + q * 16 + dd] =
            __uint_as_float(smax[(node << 4) | (dd ^ (node & 15))]);
    }
}

__global__ void k_pnorm(const float* __restrict__ p, float* __restrict__ pn) {
    int d = threadIdx.x;
    float v = p[d] * p[d];
    for (int o = 32; o > 0; o >>= 1) v += __shfl_down(v, o);
    if (d == 0) pn[0] = sqrtf(v);
}

// per-graph bitonic sort of 1024 (value,index) pairs, descending value / ascending index
__global__ void k_topk(const float* __restrict__ score, int nper, int k,
                       float* __restrict__ topv, int* __restrict__ topi) {
    __shared__ float sv[1024];
    __shared__ int   si[1024];
    int g = blockIdx.x;
    for (int i = threadIdx.x; i < 1024; i += blockDim.x) {
        sv[i] = (i < nper) ? score[g * nper + i] : -INFINITY;
        si[i] = i;
    }
    __syncthreads();
    for (int ksz = 2; ksz <= 1024; ksz <<= 1) {
        for (int j = ksz >> 1; j > 0; j >>= 1) {
            for (int i = threadIdx.x; i < 1024; i += blockDim.x) {
                int ixj = i ^ j;
                if (ixj > i) {
                    float va = sv[i], vb = sv[ixj];
                    int ia = si[i], ib = si[ixj];
                    bool up = ((i & ksz) == 0);
                    bool aBefore = (va > vb) || (va == vb && ia < ib);
                    if (up != aBefore) { sv[i] = vb; sv[ixj] = va; si[i] = ib; si[ixj] = ia; }
                }
            }
            __syncthreads();
        }
    }
    for (int i = threadIdx.x; i < k; i += blockDim.x) {
        topv[g * 1024 + i] = sv[i];
        topi[g * 1024 + i] = si[i];
    }
}

__global__ void k_init_inv(int* __restrict__ inv, int n) {
    int i = blockIdx.x * blockDim.x + threadIdx.x;
    if (i < n) inv[i] = -1;
}

// xnew[j] = x[perm[j]] * tanh(topv[j]); inv[perm[j]] = j. 4 rows per block
__global__ void k_gather(const float* __restrict__ x, const float* __restrict__ topv,
                         const int* __restrict__ topi, float* __restrict__ xnew,
                         int* __restrict__ inv, int nper, int k) {
    int w = threadIdx.x >> 6, d = threadIdx.x & 63;
    int j = blockIdx.x * 4 + w;
    int g = j / k, jj = j - g * k;
    int t = topi[g * 1024 + jj];
    int old = g * nper + t;
    float sc = tanhf(topv[g * 1024 + jj]);
    xnew[j * 64 + d] = x[old * 64 + d] * sc;
    if (d == 0) inv[old] = j;
}

__global__ void k_remap(int* __restrict__ src, int* __restrict__ dst,
                        const int* __restrict__ inv) {
    int e = blockIdx.x * blockDim.x + threadIdx.x;
    if (e >= ETOT) return;
    int s = src[e];
    if (s < 0) return;
    int ns = inv[s], nd = inv[dst[e]];
    if (ns >= 0 && nd >= 0) { src[e] = ns; dst[e] = nd; }
    else src[e] = -1;
}

// r[g] = [max over k rows, mean over k rows]; 4-way split over rows
__global__ __launch_bounds__(256) void k_readout(const float* __restrict__ x,
                                                 float* __restrict__ r, int k) {
    __shared__ float smx[4][64], ssm[4][64];
    int g = blockIdx.x;
    int d = threadIdx.x & 63, c = threadIdx.x >> 6;
    float m = -INFINITY, s = 0.f;
    for (int j = c; j < k; j += 4) {
        float v = x[((size_t)g * k + j) * 64 + d];
        m = fmaxf(m, v); s += v;
    }
    smx[c][d] = m; ssm[c][d] = s;
    __syncthreads();
    if (c == 0) {
        m = fmaxf(fmaxf(smx[0][d], smx[1][d]), fmaxf(smx[2][d], smx[3][d]));
        s = ssm[0][d] + ssm[1][d] + ssm[2][d] + ssm[3][d];
        r[g * 128 + d] = m;
        r[g * 128 + 64 + d] = s / (float)k;
    }
}

__global__ void k_mlp(const float* __restrict__ r1, const float* __restrict__ r2,
                      const float* __restrict__ r3,
                      const float* __restrict__ l1W, const float* __restrict__ l1b,
                      const float* __restrict__ l2W, const float* __restrict__ l2b,
                      const float* __restrict__ l3W, const float* __restrict__ l3b,
                      float* __restrict__ out) {
    __shared__ float h[128], h1[64], h2[64];
    int g = blockIdx.x, d = threadIdx.x;   // 64 threads
    h[d]      = r1[g*128 + d]      + r2[g*128 + d]      + r3[g*128 + d];
    h[d + 64] = r1[g*128 + 64 + d] + r2[g*128 + 64 + d] + r3[g*128 + 64 + d];
    __syncthreads();
    float a = l1b[d];
    for (int k = 0; k < 128; k++) a = fmaf(l1W[d*128 + k], h[k], a);
    h1[d] = fmaxf(a, 0.f);
    __syncthreads();
    a = l2b[d];
    for (int k = 0; k < 64; k++) a = fmaf(l2W[d*64 + k], h1[k], a);
    h2[d] = fmaxf(a, 0.f);
    __syncthreads();
    a = l3b[d];
    for (int k = 0; k < 64; k++) a = fmaf(l3W[d*64 + k], h2[k], a);
    out[g*64 + d] = 1.f / (1.f + expf(-a));
}

__global__ void k_batch(float* __restrict__ out) {
    int i = blockIdx.x * blockDim.x + threadIdx.x;
    if (i < BGRAPH * KK3) out[i] = (float)(i / KK3);
}

// ---------- launch ----------

extern "C" void kernel_launch(void* const* d_in, const int* in_sizes, int n_in,
                              void* d_out, int out_size, void* d_ws, size_t ws_size,
                              hipStream_t stream) {
    const int*   x_ids = (const int*)  d_in[0];
    const int*   eidx  = (const int*)  d_in[1];
    const float* emb   = (const float*)d_in[2];
    const float* Wl[3] = {(const float*)d_in[3],  (const float*)d_in[7],  (const float*)d_in[11]};
    const float* bl[3] = {(const float*)d_in[4],  (const float*)d_in[8],  (const float*)d_in[12]};
    const float* Ul[3] = {(const float*)d_in[5],  (const float*)d_in[9],  (const float*)d_in[13]};
    const float* pl[3] = {(const float*)d_in[6],  (const float*)d_in[10], (const float*)d_in[14]};
    const float* l1W = (const float*)d_in[15]; const float* l1b = (const float*)d_in[16];
    const float* l2W = (const float*)d_in[17]; const float* l2b = (const float*)d_in[18];
    const float* l3W = (const float*)d_in[19]; const float* l3b = (const float*)d_in[20];

    float* ws   = (float*)d_ws;
    float* xA   = ws;
    float* xB   = xA + (size_t)NTOT * DDIM;
    float* xC   = xB + (size_t)NTOT * DDIM;
    float* score= xC + (size_t)NTOT * DDIM;
    float* topv = score + NTOT;
    float* r1   = topv + BGRAPH * 1024;
    float* r2   = r1 + BGRAPH * 128;
    float* r3   = r2 + BGRAPH * 128;
    float* pn   = r3 + BGRAPH * 128;
    int*   src  = (int*)(pn + 4);
    int*   dst  = src + ETOT;
    int*   inv  = dst + ETOT;
    int*   topi = inv + NTOT;

    float* rr[3] = {r1, r2, r3};
    const int nperl[3] = {NPER0, KK1, KK2};
    const int kl[3]    = {KK1, KK2, KK3};

    k_embed<<<(NTOT * 16 + 255) / 256, 256, 0, stream>>>(x_ids, emb, (float4*)xA);
    k_copy_edges<<<(ETOT / 4 + 255) / 256, 256, 0, stream>>>((const int4*)eidx, (int4*)src, (int4*)dst);

    float *x = xA, *m = xB, *a = xC;
    int n = NTOT;
    for (int l = 0; l < 3; l++) {
        int nper = nperl[l], k = kl[l];
        // SAGE
        k_dense64<<<n / 64, 64, 0, stream>>>(x, Wl[l], bl[l], m);
        k_edge_max<<<dim3(BGRAPH, 4), 1024, nper * 16 * sizeof(float), stream>>>(src, dst, m, a, nper);
        k_pnorm<<<1, 64, 0, stream>>>(pl[l], pn);
        k_dense128cat<<<n / 64, 64, 0, stream>>>(a, x, Ul[l], pl[l], pn, m, score);
        // TopK
        k_init_inv<<<(n + 255) / 256, 256, 0, stream>>>(inv, n);
        k_topk<<<BGRAPH, 256, 0, stream>>>(score, nper, k, topv, topi);
        int nn = BGRAPH * k;
        k_gather<<<nn / 4, 256, 0, stream>>>(m, topv, topi, a, inv, nper, k);
        if (l < 2) k_remap<<<(ETOT + 255) / 256, 256, 0, stream>>>(src, dst, inv);
        k_readout<<<BGRAPH, 256, 0, stream>>>(a, rr[l], k);
        // rotate buffers: new x in a
        float* t = x; x = a; a = m; m = t;
        n = nn;
    }

    k_mlp<<<BGRAPH, 64, 0, stream>>>(r1, r2, r3, l1W, l1b, l2W, l2b, l3W, l3b, (float*)d_out);
    k_batch<<<(BGRAPH * KK3 + 255) / 256, 256, 0, stream>>>((float*)d_out + BGRAPH * DDIM);
}

// Round 4
// 1100.725 us; speedup vs baseline: 2.9437x; 1.1901x over previous
//
#include <hip/hip_runtime.h>
#include <hip/hip_bf16.h>
#include <math.h>

#define BGRAPH 128
#define NPER0 1024
#define DDIM 64
#define NTOT (BGRAPH*NPER0)      // 131072
#define ETOT (NTOT*16)           // 2097152
#define EPG  (ETOT/BGRAPH)       // 16384 edges per graph
#define KK1 820
#define KK2 656
#define KK3 525

// ---------- kernels ----------

__global__ void k_embed(const int* __restrict__ ids, const float* __restrict__ emb,
                        float4* __restrict__ x) {
    int i = blockIdx.x * blockDim.x + threadIdx.x;   // one float4 per thread
    if (i < NTOT * 16) {
        int n = i >> 4, d4 = i & 15;
        x[i] = ((const float4*)emb)[ids[n] * 16 + d4];
    }
}

__global__ void k_copy_edges(const int* __restrict__ ein, int2* __restrict__ edges) {
    int e = blockIdx.x * blockDim.x + threadIdx.x;
    if (e < ETOT) edges[e] = make_int2(ein[e], ein[ETOT + e]);
}

// msg = relu(x @ W.T + b). One node per thread, weights via uniform (SGPR) loads,
// outputs staged in LDS for coalesced write. Block = 64 threads = 64 nodes.
__global__ __launch_bounds__(64) void k_dense64(const float* __restrict__ x,
                                                const float* __restrict__ W,
                                                const float* __restrict__ b,
                                                float* __restrict__ out) {
    __shared__ float tile[64 * 65];
    int lane = threadIdx.x;
    int node0 = blockIdx.x * 64;
    int node = node0 + lane;
    float xr[64];
    const float4* xp = (const float4*)(x + (size_t)node * 64);
    #pragma unroll
    for (int i = 0; i < 16; i++) {
        float4 v = xp[i];
        xr[4*i] = v.x; xr[4*i+1] = v.y; xr[4*i+2] = v.z; xr[4*i+3] = v.w;
    }
    for (int d = 0; d < 64; d += 2) {
        float a0 = b[d], a1 = b[d + 1];
        #pragma unroll
        for (int k = 0; k < 64; k++) {
            a0 = fmaf(W[d * 64 + k],       xr[k], a0);
            a1 = fmaf(W[(d + 1) * 64 + k], xr[k], a1);
        }
        tile[lane * 65 + d]     = fmaxf(a0, 0.f);
        tile[lane * 65 + d + 1] = fmaxf(a1, 0.f);
    }
    __syncthreads();
    #pragma unroll 4
    for (int j = 0; j < 64; j++)
        out[(size_t)(node0 + j) * 64 + lane] = tile[j * 65 + lane];
}

// h = relu(concat(aggr,x) @ U.T); score = (h @ p)/||p|| fused (norm computed in-block).
__global__ __launch_bounds__(64) void k_dense128cat(const float* __restrict__ aggr,
                                                    const float* __restrict__ x,
                                                    const float* __restrict__ U,
                                                    const float* __restrict__ p,
                                                    float* __restrict__ out,
                                                    float* __restrict__ score) {
    __shared__ float tile[64 * 65];
    int lane = threadIdx.x;
    int node0 = blockIdx.x * 64;
    int node = node0 + lane;
    float xr[128];
    const float4* ap = (const float4*)(aggr + (size_t)node * 64);
    const float4* xp = (const float4*)(x    + (size_t)node * 64);
    #pragma unroll
    for (int i = 0; i < 16; i++) {
        float4 v = ap[i];
        xr[4*i] = v.x; xr[4*i+1] = v.y; xr[4*i+2] = v.z; xr[4*i+3] = v.w;
    }
    #pragma unroll
    for (int i = 0; i < 16; i++) {
        float4 v = xp[i];
        xr[64+4*i] = v.x; xr[64+4*i+1] = v.y; xr[64+4*i+2] = v.z; xr[64+4*i+3] = v.w;
    }
    // ||p|| via 64-lane butterfly
    float pv = p[lane];
    float nrm = pv * pv;
    #pragma unroll
    for (int o = 32; o > 0; o >>= 1) nrm += __shfl_xor(nrm, o);
    nrm = sqrtf(nrm);
    float sacc = 0.f;
    for (int d = 0; d < 64; d += 2) {
        float a0 = 0.f, a1 = 0.f;
        #pragma unroll
        for (int k = 0; k < 128; k++) {
            a0 = fmaf(U[d * 128 + k],       xr[k], a0);
            a1 = fmaf(U[(d + 1) * 128 + k], xr[k], a1);
        }
        a0 = fmaxf(a0, 0.f); a1 = fmaxf(a1, 0.f);
        sacc = fmaf(a0, p[d], sacc);
        sacc = fmaf(a1, p[d + 1], sacc);
        tile[lane * 65 + d]     = a0;
        tile[lane * 65 + d + 1] = a1;
    }
    score[node] = sacc / nrm;
    __syncthreads();
    #pragma unroll 4
    for (int j = 0; j < 64; j++)
        out[(size_t)(node0 + j) * 64 + lane] = tile[j * 65 + lane];
}

// Per-graph LDS max-aggregation over a 16-dim quarter, 4-way ILP on edges.
__global__ __launch_bounds__(1024) void k_edge_max(const int2* __restrict__ edges,
                                                   const float* __restrict__ msg,
                                                   float* __restrict__ aggr,
                                                   int nper) {
    extern __shared__ unsigned smax[];   // [nper][16], xor-swizzled
    int g = blockIdx.x, q = blockIdx.y;
    int t = threadIdx.x;
    int d = t & 15, es = t >> 4;         // 16 dims x 64 edge slots
    int nodebase = g * nper;
    int q16 = q * 16;
    for (int i = t; i < nper * 16; i += 1024) {
        int node = i >> 4, dd = i & 15;
        float v = msg[(size_t)(nodebase + node) * 64 + q16 + dd];
        smax[(node << 4) | (dd ^ (node & 15))] = __float_as_uint(v);
    }
    __syncthreads();
    const int2* eb = edges + g * EPG;
    for (int base = 0; base < EPG; base += 256) {   // 64 iterations, 4 edges/thread
        int2 sd[4];
        float v[4];
        #pragma unroll
        for (int u = 0; u < 4; u++) sd[u] = eb[base + u * 64 + es];
        #pragma unroll
        for (int u = 0; u < 4; u++)
            v[u] = (sd[u].x >= 0) ? msg[(size_t)sd[u].x * 64 + q16 + d] : 0.f;
        #pragma unroll
        for (int u = 0; u < 4; u++) {
            if (sd[u].x >= 0) {
                int ln = sd[u].y - nodebase;
                atomicMax(&smax[(ln << 4) | (d ^ (ln & 15))], __float_as_uint(v[u]));
            }
        }
    }
    __syncthreads();
    for (int i = t; i < nper * 16; i += 1024) {
        int node = i >> 4, dd = i & 15;
        aggr[(size_t)(nodebase + node) * 64 + q16 + dd] =
            __uint_as_float(smax[(node << 4) | (dd ^ (node & 15))]);
    }
}

// per-graph bitonic sort of 1024 (value,index) pairs, desc value / asc index.
// Writes topv/topi AND the inverse permutation (selected -> new id, else -1).
__global__ __launch_bounds__(1024) void k_topk(const float* __restrict__ score,
                                               int nper, int k,
                                               float* __restrict__ topv,
                                               int* __restrict__ topi,
                                               int* __restrict__ inv) {
    __shared__ float sv[1024];
    __shared__ int   si[1024];
    int g = blockIdx.x;
    int i = threadIdx.x;
    sv[i] = (i < nper) ? score[g * nper + i] : -INFINITY;
    si[i] = i;
    __syncthreads();
    for (int ksz = 2; ksz <= 1024; ksz <<= 1) {
        for (int j = ksz >> 1; j > 0; j >>= 1) {
            int ixj = i ^ j;
            if (ixj > i) {
                float va = sv[i], vb = sv[ixj];
                int ia = si[i], ib = si[ixj];
                bool up = ((i & ksz) == 0);
                bool aBefore = (va > vb) || (va == vb && ia < ib);
                if (up != aBefore) { sv[i] = vb; sv[ixj] = va; si[i] = ib; si[ixj] = ia; }
            }
            __syncthreads();
        }
    }
    if (i < k) { topv[g * 1024 + i] = sv[i]; topi[g * 1024 + i] = si[i]; }
    int s = si[i];
    if (s < nper) inv[g * nper + s] = (i < k) ? (g * k + i) : -1;
}

// xnew[j] = x[perm[j]] * tanh(topv[j]). 4 rows per block
__global__ void k_gather(const float* __restrict__ x, const float* __restrict__ topv,
                         const int* __restrict__ topi, float* __restrict__ xnew,
                         int nper, int k) {
    int w = threadIdx.x >> 6, d = threadIdx.x & 63;
    int j = blockIdx.x * 4 + w;
    int g = j / k, jj = j - g * k;
    int t = topi[g * 1024 + jj];
    int old = g * nper + t;
    float sc = tanhf(topv[g * 1024 + jj]);
    xnew[j * 64 + d] = x[old * 64 + d] * sc;
}

__global__ void k_remap(int2* __restrict__ edges, const int* __restrict__ inv) {
    int e = blockIdx.x * blockDim.x + threadIdx.x;
    if (e >= ETOT) return;
    int2 sd = edges[e];
    if (sd.x < 0) return;
    int ns = inv[sd.x], nd = inv[sd.y];
    edges[e] = (ns >= 0 && nd >= 0) ? make_int2(ns, nd) : make_int2(-1, sd.y);
}

// r[g] = [max over k rows, mean over k rows]; 4-way split over rows
__global__ __launch_bounds__(256) void k_readout(const float* __restrict__ x,
                                                 float* __restrict__ r, int k) {
    __shared__ float smx[4][64], ssm[4][64];
    int g = blockIdx.x;
    int d = threadIdx.x & 63, c = threadIdx.x >> 6;
    float m = -INFINITY, s = 0.f;
    for (int j = c; j < k; j += 4) {
        float v = x[((size_t)g * k + j) * 64 + d];
        m = fmaxf(m, v); s += v;
    }
    smx[c][d] = m; ssm[c][d] = s;
    __syncthreads();
    if (c == 0) {
        m = fmaxf(fmaxf(smx[0][d], smx[1][d]), fmaxf(smx[2][d], smx[3][d]));
        s = ssm[0][d] + ssm[1][d] + ssm[2][d] + ssm[3][d];
        r[g * 128 + d] = m;
        r[g * 128 + 64 + d] = s / (float)k;
    }
}

__global__ void k_mlp(const float* __restrict__ r1, const float* __restrict__ r2,
                      const float* __restrict__ r3,
                      const float* __restrict__ l1W, const float* __restrict__ l1b,
                      const float* __restrict__ l2W, const float* __restrict__ l2b,
                      const float* __restrict__ l3W, const float* __restrict__ l3b,
                      float* __restrict__ out) {
    __shared__ float h[128], h1[64], h2[64];
    int g = blockIdx.x, d = threadIdx.x;   // 64 threads
    h[d]      = r1[g*128 + d]      + r2[g*128 + d]      + r3[g*128 + d];
    h[d + 64] = r1[g*128 + 64 + d] + r2[g*128 + 64 + d] + r3[g*128 + 64 + d];
    __syncthreads();
    float a = l1b[d];
    for (int k = 0; k < 128; k++) a = fmaf(l1W[d*128 + k], h[k], a);
    h1[d] = fmaxf(a, 0.f);
    __syncthreads();
    a = l2b[d];
    for (int k = 0; k < 64; k++) a = fmaf(l2W[d*64 + k], h1[k], a);
    h2[d] = fmaxf(a, 0.f);
    __syncthreads();
    a = l3b[d];
    for (int k = 0; k < 64; k++) a = fmaf(l3W[d*64 + k], h2[k], a);
    out[g*64 + d] = 1.f / (1.f + expf(-a));
}

__global__ void k_batch(float* __restrict__ out) {
    int i = blockIdx.x * blockDim.x + threadIdx.x;
    if (i < BGRAPH * KK3) out[i] = (float)(i / KK3);
}

// ---------- launch ----------

extern "C" void kernel_launch(void* const* d_in, const int* in_sizes, int n_in,
                              void* d_out, int out_size, void* d_ws, size_t ws_size,
                              hipStream_t stream) {
    const int*   x_ids = (const int*)  d_in[0];
    const int*   eidx  = (const int*)  d_in[1];
    const float* emb   = (const float*)d_in[2];
    const float* Wl[3] = {(const float*)d_in[3],  (const float*)d_in[7],  (const float*)d_in[11]};
    const float* bl[3] = {(const float*)d_in[4],  (const float*)d_in[8],  (const float*)d_in[12]};
    const float* Ul[3] = {(const float*)d_in[5],  (const float*)d_in[9],  (const float*)d_in[13]};
    const float* pl[3] = {(const float*)d_in[6],  (const float*)d_in[10], (const float*)d_in[14]};
    const float* l1W = (const float*)d_in[15]; const float* l1b = (const float*)d_in[16];
    const float* l2W = (const float*)d_in[17]; const float* l2b = (const float*)d_in[18];
    const float* l3W = (const float*)d_in[19]; const float* l3b = (const float*)d_in[20];

    float* ws   = (float*)d_ws;
    float* xA   = ws;
    float* xB   = xA + (size_t)NTOT * DDIM;
    float* xC   = xB + (size_t)NTOT * DDIM;
    float* score= xC + (size_t)NTOT * DDIM;
    float* topv = score + NTOT;
    float* r1   = topv + BGRAPH * 1024;
    float* r2   = r1 + BGRAPH * 128;
    float* r3   = r2 + BGRAPH * 128;
    int2*  edges= (int2*)(r3 + BGRAPH * 128);
    int*   inv  = (int*)(edges + ETOT);
    int*   topi = inv + NTOT;

    float* rr[3] = {r1, r2, r3};
    const int nperl[3] = {NPER0, KK1, KK2};
    const int kl[3]    = {KK1, KK2, KK3};

    k_embed<<<(NTOT * 16 + 255) / 256, 256, 0, stream>>>(x_ids, emb, (float4*)xA);
    k_copy_edges<<<(ETOT + 255) / 256, 256, 0, stream>>>(eidx, edges);

    float *x = xA, *m = xB, *a = xC;
    int n = NTOT;
    for (int l = 0; l < 3; l++) {
        int nper = nperl[l], k = kl[l];
        // SAGE
        k_dense64<<<n / 64, 64, 0, stream>>>(x, Wl[l], bl[l], m);
        k_edge_max<<<dim3(BGRAPH, 4), 1024, nper * 16 * sizeof(float), stream>>>(edges, m, a, nper);
        k_dense128cat<<<n / 64, 64, 0, stream>>>(a, x, Ul[l], pl[l], m, score);
        // TopK
        k_topk<<<BGRAPH, 1024, 0, stream>>>(score, nper, k, topv, topi, inv);
        int nn = BGRAPH * k;
        k_gather<<<nn / 4, 256, 0, stream>>>(m, topv, topi, a, nper, k);
        if (l < 2) k_remap<<<(ETOT + 255) / 256, 256, 0, stream>>>(edges, inv);
        k_readout<<<BGRAPH, 256, 0, stream>>>(a, rr[l], k);
        // rotate buffers: new x in a
        float* t = x; x = a; a = m; m = t;
        n = nn;
    }

    k_mlp<<<BGRAPH, 64, 0, stream>>>(r1, r2, r3, l1W, l1b, l2W, l2b, l3W, l3b, (float*)d_out);
    k_batch<<<(BGRAPH * KK3 + 255) / 256, 256, 0, stream>>>((float*)d_out + BGRAPH * DDIM);
}

// Round 5
// 839.927 us; speedup vs baseline: 3.8577x; 1.3105x over previous
//
#include <hip/hip_runtime.h>
#include <hip/hip_bf16.h>
#include <math.h>

#define BGRAPH 128
#define NPER0 1024
#define DDIM 64
#define NTOT (BGRAPH*NPER0)      // 131072
#define ETOT (NTOT*16)           // 2097152
#define EPG  (ETOT/BGRAPH)       // 16384 edges per graph
#define KK1 820
#define KK2 656
#define KK3 525

// ---------- kernels ----------

__global__ void k_embed(const int* __restrict__ ids, const float* __restrict__ emb,
                        float4* __restrict__ x) {
    int i = blockIdx.x * blockDim.x + threadIdx.x;   // one float4 per thread
    if (i < NTOT * 16) {
        int n = i >> 4, d4 = i & 15;
        x[i] = ((const float4*)emb)[ids[n] * 16 + d4];
    }
}

__global__ void k_copy_edges(const int* __restrict__ ein, int2* __restrict__ edges) {
    int e = blockIdx.x * blockDim.x + threadIdx.x;
    if (e < ETOT) edges[e] = make_int2(ein[e], ein[ETOT + e]);
}

// msg = relu(x @ W.T + b). One node per thread, SGPR weight loads, chunked LDS
// staging (16 output dims at a time) for coalesced writes. 128 threads/block.
__global__ __launch_bounds__(128) void k_dense64(const float* __restrict__ x,
                                                 const float* __restrict__ W,
                                                 const float* __restrict__ b,
                                                 float* __restrict__ out) {
    __shared__ float tile[128 * 17];
    int t = threadIdx.x;
    int node0 = blockIdx.x * 128;
    int node = node0 + t;
    float xr[64];
    const float4* xp = (const float4*)(x + (size_t)node * 64);
    #pragma unroll
    for (int i = 0; i < 16; i++) {
        float4 v = xp[i];
        xr[4*i] = v.x; xr[4*i+1] = v.y; xr[4*i+2] = v.z; xr[4*i+3] = v.w;
    }
    int col = t & 15, r0 = t >> 4;
    for (int c = 0; c < 4; c++) {
        #pragma unroll
        for (int di = 0; di < 4; di++) {
            int d = c * 16 + di * 4;
            float a0 = b[d], a1 = b[d+1], a2 = b[d+2], a3 = b[d+3];
            #pragma unroll
            for (int k = 0; k < 64; k++) {
                a0 = fmaf(W[(d+0) * 64 + k], xr[k], a0);
                a1 = fmaf(W[(d+1) * 64 + k], xr[k], a1);
                a2 = fmaf(W[(d+2) * 64 + k], xr[k], a2);
                a3 = fmaf(W[(d+3) * 64 + k], xr[k], a3);
            }
            tile[t * 17 + di*4 + 0] = fmaxf(a0, 0.f);
            tile[t * 17 + di*4 + 1] = fmaxf(a1, 0.f);
            tile[t * 17 + di*4 + 2] = fmaxf(a2, 0.f);
            tile[t * 17 + di*4 + 3] = fmaxf(a3, 0.f);
        }
        __syncthreads();
        #pragma unroll
        for (int it = 0; it < 16; it++) {
            int row = r0 + it * 8;
            out[(size_t)(node0 + row) * 64 + c * 16 + col] = tile[row * 17 + col];
        }
        __syncthreads();
    }
}

// h = relu(concat(aggr,x) @ U.T); score = (h @ p)/||p|| fused. Chunked staging.
__global__ __launch_bounds__(128) void k_dense128cat(const float* __restrict__ aggr,
                                                     const float* __restrict__ x,
                                                     const float* __restrict__ U,
                                                     const float* __restrict__ p,
                                                     float* __restrict__ out,
                                                     float* __restrict__ score) {
    __shared__ float tile[128 * 17];
    int t = threadIdx.x;
    int node0 = blockIdx.x * 128;
    int node = node0 + t;
    float xr[128];
    const float4* ap = (const float4*)(aggr + (size_t)node * 64);
    const float4* xp = (const float4*)(x    + (size_t)node * 64);
    #pragma unroll
    for (int i = 0; i < 16; i++) {
        float4 v = ap[i];
        xr[4*i] = v.x; xr[4*i+1] = v.y; xr[4*i+2] = v.z; xr[4*i+3] = v.w;
    }
    #pragma unroll
    for (int i = 0; i < 16; i++) {
        float4 v = xp[i];
        xr[64+4*i] = v.x; xr[64+4*i+1] = v.y; xr[64+4*i+2] = v.z; xr[64+4*i+3] = v.w;
    }
    float pv = p[t & 63];
    float nrm = pv * pv;
    #pragma unroll
    for (int o = 32; o > 0; o >>= 1) nrm += __shfl_xor(nrm, o);
    nrm = sqrtf(nrm);
    float sacc = 0.f;
    int col = t & 15, r0 = t >> 4;
    for (int c = 0; c < 4; c++) {
        #pragma unroll
        for (int di = 0; di < 4; di++) {
            int d = c * 16 + di * 4;
            float a0 = 0.f, a1 = 0.f, a2 = 0.f, a3 = 0.f;
            #pragma unroll
            for (int k = 0; k < 128; k++) {
                a0 = fmaf(U[(d+0) * 128 + k], xr[k], a0);
                a1 = fmaf(U[(d+1) * 128 + k], xr[k], a1);
                a2 = fmaf(U[(d+2) * 128 + k], xr[k], a2);
                a3 = fmaf(U[(d+3) * 128 + k], xr[k], a3);
            }
            a0 = fmaxf(a0, 0.f); a1 = fmaxf(a1, 0.f);
            a2 = fmaxf(a2, 0.f); a3 = fmaxf(a3, 0.f);
            sacc = fmaf(a0, p[d+0], sacc); sacc = fmaf(a1, p[d+1], sacc);
            sacc = fmaf(a2, p[d+2], sacc); sacc = fmaf(a3, p[d+3], sacc);
            tile[t * 17 + di*4 + 0] = a0;
            tile[t * 17 + di*4 + 1] = a1;
            tile[t * 17 + di*4 + 2] = a2;
            tile[t * 17 + di*4 + 3] = a3;
        }
        __syncthreads();
        #pragma unroll
        for (int it = 0; it < 16; it++) {
            int row = r0 + it * 8;
            out[(size_t)(node0 + row) * 64 + c * 16 + col] = tile[row * 17 + col];
        }
        __syncthreads();
    }
    score[node] = sacc / nrm;
}

// Per-graph LDS max-aggregation over a 16-dim quarter. 4 lanes/edge x float4.
__global__ __launch_bounds__(1024) void k_edge_max(const int2* __restrict__ edges,
                                                   const float4* __restrict__ msg4,
                                                   float4* __restrict__ aggr4,
                                                   int nper) {
    extern __shared__ unsigned smax[];   // [nper][16] dwords, xor-swizzled
    int g = blockIdx.x, q = blockIdx.y;
    int t = threadIdx.x;
    int nodebase = g * nper;
    int q4 = q * 4;                      // float4 offset within 16-f4 row
    for (int i = t; i < nper * 4; i += 1024) {
        int node = i >> 2, dd = (i & 3) * 4;
        float4 v = msg4[(size_t)(nodebase + node) * 16 + q4 + (i & 3)];
        int b0 = node << 4, sw = node & 15;
        smax[b0 | ((dd+0) ^ sw)] = __float_as_uint(v.x);
        smax[b0 | ((dd+1) ^ sw)] = __float_as_uint(v.y);
        smax[b0 | ((dd+2) ^ sw)] = __float_as_uint(v.z);
        smax[b0 | ((dd+3) ^ sw)] = __float_as_uint(v.w);
    }
    __syncthreads();
    const int2* eb = edges + g * EPG;
    int f4 = t & 3, d4 = f4 * 4, es = t >> 2;   // 256 edge slots
    for (int base = 0; base < EPG; base += 1024) {   // 16 iters, 4 edges/thread
        int2 sd[4];
        float4 v[4];
        #pragma unroll
        for (int u = 0; u < 4; u++) sd[u] = eb[base + u * 256 + es];
        #pragma unroll
        for (int u = 0; u < 4; u++)
            v[u] = (sd[u].x >= 0) ? msg4[(size_t)sd[u].x * 16 + q4 + f4]
                                  : make_float4(0.f, 0.f, 0.f, 0.f);
        #pragma unroll
        for (int u = 0; u < 4; u++) {
            if (sd[u].x >= 0) {
                int ln = sd[u].y - nodebase;
                int b0 = ln << 4, sw = ln & 15;
                atomicMax(&smax[b0 | ((d4+0) ^ sw)], __float_as_uint(v[u].x));
                atomicMax(&smax[b0 | ((d4+1) ^ sw)], __float_as_uint(v[u].y));
                atomicMax(&smax[b0 | ((d4+2) ^ sw)], __float_as_uint(v[u].z));
                atomicMax(&smax[b0 | ((d4+3) ^ sw)], __float_as_uint(v[u].w));
            }
        }
    }
    __syncthreads();
    for (int i = t; i < nper * 4; i += 1024) {
        int node = i >> 2, dd = (i & 3) * 4;
        int b0 = node << 4, sw = node & 15;
        float4 v;
        v.x = __uint_as_float(smax[b0 | ((dd+0) ^ sw)]);
        v.y = __uint_as_float(smax[b0 | ((dd+1) ^ sw)]);
        v.z = __uint_as_float(smax[b0 | ((dd+2) ^ sw)]);
        v.w = __uint_as_float(smax[b0 | ((dd+3) ^ sw)]);
        aggr4[(size_t)(nodebase + node) * 16 + q4 + (i & 3)] = v;
    }
}

// per-graph bitonic sort (desc value / asc index) + in-LDS inverse perm +
// in-place edge remap for this graph (edges only reference their own graph).
__global__ __launch_bounds__(1024) void k_topk_remap(const float* __restrict__ score,
                                                     int nper, int k,
                                                     float* __restrict__ topv,
                                                     int* __restrict__ topi,
                                                     int2* __restrict__ edges,
                                                     int do_remap) {
    __shared__ float sv[1024];
    __shared__ int   si[1024];
    __shared__ int   invl[1024];
    int g = blockIdx.x;
    int i = threadIdx.x;
    sv[i] = (i < nper) ? score[g * nper + i] : -INFINITY;
    si[i] = i;
    __syncthreads();
    for (int ksz = 2; ksz <= 1024; ksz <<= 1) {
        for (int j = ksz >> 1; j > 0; j >>= 1) {
            int ixj = i ^ j;
            if (ixj > i) {
                float va = sv[i], vb = sv[ixj];
                int ia = si[i], ib = si[ixj];
                bool up = ((i & ksz) == 0);
                bool aBefore = (va > vb) || (va == vb && ia < ib);
                if (up != aBefore) { sv[i] = vb; sv[ixj] = va; si[i] = ib; si[ixj] = ia; }
            }
            __syncthreads();
        }
    }
    if (i < k) { topv[g * 1024 + i] = sv[i]; topi[g * 1024 + i] = si[i]; }
    int s = si[i];
    if (s < nper) invl[s] = (i < k) ? (g * k + i) : -1;
    __syncthreads();
    if (do_remap) {
        int2* eb = edges + g * EPG;
        int nb = g * nper;
        for (int e = i; e < EPG; e += 1024) {
            int2 sd = eb[e];
            if (sd.x < 0) continue;
            int ns = invl[sd.x - nb], nd = invl[sd.y - nb];
            eb[e] = (ns >= 0 && nd >= 0) ? make_int2(ns, nd) : make_int2(-1, sd.y);
        }
    }
}

// xnew[j] = x[perm[j]] * tanh(topv[j]) fused with readout (max/mean over rows).
__global__ __launch_bounds__(1024) void k_gather_readout(const float* __restrict__ x,
                                                         const float* __restrict__ topv,
                                                         const int* __restrict__ topi,
                                                         float* __restrict__ xnew,
                                                         float* __restrict__ r,
                                                         int nper, int k) {
    __shared__ float sscale[1024];
    __shared__ float smx[16][64], ssm[16][64];
    int g = blockIdx.x, t = threadIdx.x;
    if (t < k) sscale[t] = tanhf(topv[g * 1024 + t]);
    __syncthreads();
    int d = t & 63, c = t >> 6;
    float m = -INFINITY, s = 0.f;
    for (int j = c; j < k; j += 16) {
        int src = topi[g * 1024 + j];
        float v = x[((size_t)(g * nper) + src) * 64 + d] * sscale[j];
        xnew[((size_t)g * k + j) * 64 + d] = v;
        m = fmaxf(m, v); s += v;
    }
    smx[c][d] = m; ssm[c][d] = s;
    __syncthreads();
    if (c == 0) {
        #pragma unroll
        for (int u = 1; u < 16; u++) { m = fmaxf(m, smx[u][d]); s += ssm[u][d]; }
        r[g * 128 + d] = m;
        r[g * 128 + 64 + d] = s / (float)k;
    }
}

__global__ void k_mlp(const float* __restrict__ r1, const float* __restrict__ r2,
                      const float* __restrict__ r3,
                      const float* __restrict__ l1W, const float* __restrict__ l1b,
                      const float* __restrict__ l2W, const float* __restrict__ l2b,
                      const float* __restrict__ l3W, const float* __restrict__ l3b,
                      float* __restrict__ out) {
    __shared__ float h[128], h1[64], h2[64];
    int g = blockIdx.x, d = threadIdx.x;   // 64 threads
    h[d]      = r1[g*128 + d]      + r2[g*128 + d]      + r3[g*128 + d];
    h[d + 64] = r1[g*128 + 64 + d] + r2[g*128 + 64 + d] + r3[g*128 + 64 + d];
    __syncthreads();
    float a = l1b[d];
    for (int k = 0; k < 128; k++) a = fmaf(l1W[d*128 + k], h[k], a);
    h1[d] = fmaxf(a, 0.f);
    __syncthreads();
    a = l2b[d];
    for (int k = 0; k < 64; k++) a = fmaf(l2W[d*64 + k], h1[k], a);
    h2[d] = fmaxf(a, 0.f);
    __syncthreads();
    a = l3b[d];
    for (int k = 0; k < 64; k++) a = fmaf(l3W[d*64 + k], h2[k], a);
    out[g*64 + d] = 1.f / (1.f + expf(-a));
}

__global__ void k_batch(float* __restrict__ out) {
    int i = blockIdx.x * blockDim.x + threadIdx.x;
    if (i < BGRAPH * KK3) out[i] = (float)(i / KK3);
}

// ---------- launch ----------

extern "C" void kernel_launch(void* const* d_in, const int* in_sizes, int n_in,
                              void* d_out, int out_size, void* d_ws, size_t ws_size,
                              hipStream_t stream) {
    const int*   x_ids = (const int*)  d_in[0];
    const int*   eidx  = (const int*)  d_in[1];
    const float* emb   = (const float*)d_in[2];
    const float* Wl[3] = {(const float*)d_in[3],  (const float*)d_in[7],  (const float*)d_in[11]};
    const float* bl[3] = {(const float*)d_in[4],  (const float*)d_in[8],  (const float*)d_in[12]};
    const float* Ul[3] = {(const float*)d_in[5],  (const float*)d_in[9],  (const float*)d_in[13]};
    const float* pl[3] = {(const float*)d_in[6],  (const float*)d_in[10], (const float*)d_in[14]};
    const float* l1W = (const float*)d_in[15]; const float* l1b = (const float*)d_in[16];
    const float* l2W = (const float*)d_in[17]; const float* l2b = (const float*)d_in[18];
    const float* l3W = (const float*)d_in[19]; const float* l3b = (const float*)d_in[20];

    float* ws   = (float*)d_ws;
    float* xA   = ws;
    float* xB   = xA + (size_t)NTOT * DDIM;
    float* xC   = xB + (size_t)NTOT * DDIM;
    float* score= xC + (size_t)NTOT * DDIM;
    float* topv = score + NTOT;
    float* r1   = topv + BGRAPH * 1024;
    float* r2   = r1 + BGRAPH * 128;
    float* r3   = r2 + BGRAPH * 128;
    int2*  edges= (int2*)(r3 + BGRAPH * 128);
    int*   topi = (int*)(edges + ETOT);

    float* rr[3] = {r1, r2, r3};
    const int nperl[3] = {NPER0, KK1, KK2};
    const int kl[3]    = {KK1, KK2, KK3};

    k_embed<<<(NTOT * 16 + 255) / 256, 256, 0, stream>>>(x_ids, emb, (float4*)xA);
    k_copy_edges<<<(ETOT + 255) / 256, 256, 0, stream>>>(eidx, edges);

    float *x = xA, *m = xB, *a = xC;
    int n = NTOT;
    for (int l = 0; l < 3; l++) {
        int nper = nperl[l], k = kl[l];
        k_dense64<<<n / 128, 128, 0, stream>>>(x, Wl[l], bl[l], m);
        k_edge_max<<<dim3(BGRAPH, 4), 1024, nper * 16 * sizeof(float), stream>>>(
            edges, (const float4*)m, (float4*)a, nper);
        k_dense128cat<<<n / 128, 128, 0, stream>>>(a, x, Ul[l], pl[l], m, score);
        k_topk_remap<<<BGRAPH, 1024, 0, stream>>>(score, nper, k, topv, topi, edges,
                                                  (l < 2) ? 1 : 0);
        k_gather_readout<<<BGRAPH, 1024, 0, stream>>>(m, topv, topi, a, rr[l], nper, k);
        float* t = x; x = a; a = m; m = t;
        n = BGRAPH * k;
    }

    k_mlp<<<BGRAPH, 64, 0, stream>>>(r1, r2, r3, l1W, l1b, l2W, l2b, l3W, l3b, (float*)d_out);
    k_batch<<<(BGRAPH * KK3 + 255) / 256, 256, 0, stream>>>((float*)d_out + BGRAPH * DDIM);
}

// Round 7
// 545.186 us; speedup vs baseline: 5.9432x; 1.5406x over previous
//
#include <hip/hip_runtime.h>
#include <hip/hip_bf16.h>
#include <math.h>

#define BGRAPH 128
#define NPER0 1024
#define DDIM 64
#define NTOT (BGRAPH*NPER0)      // 131072
#define ETOT (NTOT*16)           // 2097152
#define EPG  (ETOT/BGRAPH)       // 16384 edges per graph
#define KK1 820
#define KK2 656
#define KK3 525

// ---------- tiny utility ----------
__global__ void k_zero(unsigned* __restrict__ p, int n) {
    int i = blockIdx.x * blockDim.x + threadIdx.x;
    if (i < n) p[i] = 0u;
}

__global__ void k_copy_edges(const int* __restrict__ ein, int2* __restrict__ edges) {
    int e = blockIdx.x * blockDim.x + threadIdx.x;
    if (e < ETOT) edges[e] = make_int2(ein[e], ein[ETOT + e]);
}

// ---------- layer-1 combo tables ----------

// msgT[id][d] = relu(b[d] + emb[id]·W[d])   (4 x 64)
__global__ void k_msg1_table(const float* __restrict__ emb, const float* __restrict__ W,
                             const float* __restrict__ b, float* __restrict__ msgT) {
    int id = blockIdx.x, d = threadIdx.x;
    float a = b[d];
    for (int k = 0; k < 64; k++) a = fmaf(emb[id * 64 + k], W[d * 64 + k], a);
    msgT[id * 64 + d] = fmaxf(a, 0.f);
}

// For combo c = mask*4+id: h1T[c][d] = relu(cat(max_{i in mask} msgT[i], emb[id])·U[d])
// s1T[c] = h1T[c]·p/||p|| ; x2T[c][d] = h1T[c][d]*tanh(s1T[c])
__global__ void k_combo1_table(const float* __restrict__ msgT, const float* __restrict__ emb,
                               const float* __restrict__ U, const float* __restrict__ p,
                               float* __restrict__ s1T, float* __restrict__ x2T) {
    __shared__ float cat[128];
    int c = blockIdx.x, d = threadIdx.x;   // 64 blocks x 64 threads
    int mask = c >> 2, id = c & 3;
    float ag = -INFINITY;
    for (int i = 0; i < 4; i++) if (mask & (1 << i)) ag = fmaxf(ag, msgT[i * 64 + d]);
    if (mask == 0) ag = 0.f;               // unused combos, keep finite
    cat[d] = ag; cat[64 + d] = emb[id * 64 + d];
    __syncthreads();
    float a = 0.f;
    for (int k = 0; k < 128; k++) a = fmaf(U[d * 128 + k], cat[k], a);
    a = fmaxf(a, 0.f);
    float pv = p[d];
    float nrm = pv * pv, sv = a * pv;
    #pragma unroll
    for (int o = 32; o > 0; o >>= 1) { nrm += __shfl_xor(nrm, o); sv += __shfl_xor(sv, o); }
    float sc = sv / sqrtf(nrm);
    if (d == 0) s1T[c] = sc;
    x2T[c * 64 + d] = a * tanhf(sc);
}

// gmask1[dst] |= 1 << x_ids[src]  over all raw edges
__global__ void k_mask1(const int* __restrict__ ein, const int* __restrict__ ids,
                        unsigned* __restrict__ gmask) {
    int e = blockIdx.x * blockDim.x + threadIdx.x;
    if (e < ETOT) atomicOr(&gmask[ein[ETOT + e]], 1u << ids[ein[e]]);
}

__global__ void k_combo1(const unsigned* __restrict__ gmask, const int* __restrict__ ids,
                         int* __restrict__ combo) {
    int i = blockIdx.x * blockDim.x + threadIdx.x;
    if (i < NTOT) {
        int id = ids[i];
        combo[i] = (int)(((gmask[i] | (1u << id)) << 2) | (unsigned)id);
    }
}

// ---------- layer-2 combo tables / mask aggregation ----------

// msg2T[c][d] = relu(b[d] + x2T[c]·W[d])   (64 x 64)
__global__ void k_msg2_table(const float* __restrict__ x2T, const float* __restrict__ W,
                             const float* __restrict__ b, float* __restrict__ msg2T) {
    int c = blockIdx.x, d = threadIdx.x;
    float a = b[d];
    for (int k = 0; k < 64; k++) a = fmaf(x2T[c * 64 + k], W[d * 64 + k], a);
    msg2T[c * 64 + d] = fmaxf(a, 0.f);
}

__global__ void k_mask2_init(const int* __restrict__ combo2, unsigned* __restrict__ m2, int n) {
    int i = blockIdx.x * blockDim.x + threadIdx.x;
    if (i < n) {
        int c = combo2[i];
        m2[i * 2]     = (c < 32) ? (1u << c) : 0u;
        m2[i * 2 + 1] = (c < 32) ? 0u : (1u << (c - 32));
    }
}

__global__ void k_mask2_edge(const int2* __restrict__ edges, const int* __restrict__ combo2,
                             unsigned* __restrict__ m2) {
    int e = blockIdx.x * blockDim.x + threadIdx.x;
    if (e >= ETOT) return;
    int2 sd = edges[e];
    if (sd.x < 0) return;
    int c = combo2[sd.x];
    atomicOr(&m2[sd.y * 2 + (c >> 5)], 1u << (c & 31));
}

// aggr[node][16 f4] = max over set bits of msg2T
__global__ void k_aggr2(const unsigned* __restrict__ m2, const float4* __restrict__ tab4,
                        float4* __restrict__ aggr4, int n) {
    int i = blockIdx.x * blockDim.x + threadIdx.x;
    if (i >= n * 16) return;
    int node = i >> 4, f = i & 15;
    unsigned lo = m2[node * 2], hi = m2[node * 2 + 1];
    float4 a = make_float4(-INFINITY, -INFINITY, -INFINITY, -INFINITY);
    while (lo) {
        int bb = __ffs(lo) - 1; lo &= lo - 1;
        float4 v = tab4[bb * 16 + f];
        a.x = fmaxf(a.x, v.x); a.y = fmaxf(a.y, v.y);
        a.z = fmaxf(a.z, v.z); a.w = fmaxf(a.w, v.w);
    }
    while (hi) {
        int bb = __ffs(hi) - 1; hi &= hi - 1;
        float4 v = tab4[(32 + bb) * 16 + f];
        a.x = fmaxf(a.x, v.x); a.y = fmaxf(a.y, v.y);
        a.z = fmaxf(a.z, v.z); a.w = fmaxf(a.w, v.w);
    }
    aggr4[(size_t)node * 16 + f] = a;
}

// ---------- real dense kernels (weights staged in LDS) ----------

// msg = relu(x @ W.T + b), W (64x64) in LDS, node per thread, direct f4 stores.
__global__ __launch_bounds__(128) void k_dense64(const float* __restrict__ x,
                                                 const float* __restrict__ W,
                                                 const float* __restrict__ b,
                                                 float* __restrict__ out) {
    __shared__ float4 Wsh[64 * 16];   // 16 KB
    int t = threadIdx.x;
    const float4* W4 = (const float4*)W;
    #pragma unroll
    for (int i = 0; i < 8; i++) Wsh[t + i * 128] = W4[t + i * 128];
    int node = blockIdx.x * 128 + t;
    float4 xr[16];
    const float4* xp = (const float4*)(x + (size_t)node * 64);
    #pragma unroll
    for (int i = 0; i < 16; i++) xr[i] = xp[i];
    __syncthreads();
    float4* op = (float4*)(out + (size_t)node * 64);
    #pragma unroll 1
    for (int d4 = 0; d4 < 16; d4++) {
        int d = d4 * 4;
        float a0 = b[d], a1 = b[d+1], a2 = b[d+2], a3 = b[d+3];
        #pragma unroll
        for (int kk = 0; kk < 16; kk++) {
            float4 xv = xr[kk];
            float4 w0 = Wsh[(d+0)*16+kk], w1 = Wsh[(d+1)*16+kk];
            float4 w2 = Wsh[(d+2)*16+kk], w3 = Wsh[(d+3)*16+kk];
            a0 = fmaf(w0.w,xv.w,fmaf(w0.z,xv.z,fmaf(w0.y,xv.y,fmaf(w0.x,xv.x,a0))));
            a1 = fmaf(w1.w,xv.w,fmaf(w1.z,xv.z,fmaf(w1.y,xv.y,fmaf(w1.x,xv.x,a1))));
            a2 = fmaf(w2.w,xv.w,fmaf(w2.z,xv.z,fmaf(w2.y,xv.y,fmaf(w2.x,xv.x,a2))));
            a3 = fmaf(w3.w,xv.w,fmaf(w3.z,xv.z,fmaf(w3.y,xv.y,fmaf(w3.x,xv.x,a3))));
        }
        op[d4] = make_float4(fmaxf(a0,0.f), fmaxf(a1,0.f), fmaxf(a2,0.f), fmaxf(a3,0.f));
    }
}

// h = relu(cat(aggr,x) @ U.T); score = h·p/||p||. U (64x128) in LDS.
__global__ __launch_bounds__(128) void k_dense128cat(const float* __restrict__ aggr,
                                                     const float* __restrict__ x,
                                                     const float* __restrict__ U,
                                                     const float* __restrict__ p,
                                                     float* __restrict__ out,
                                                     float* __restrict__ score) {
    __shared__ float4 Ush[64 * 32];   // 32 KB
    int t = threadIdx.x;
    const float4* U4 = (const float4*)U;
    #pragma unroll
    for (int i = 0; i < 16; i++) Ush[t + i * 128] = U4[t + i * 128];
    int node = blockIdx.x * 128 + t;
    float4 xr[32];
    const float4* ap = (const float4*)(aggr + (size_t)node * 64);
    const float4* xp = (const float4*)(x    + (size_t)node * 64);
    #pragma unroll
    for (int i = 0; i < 16; i++) xr[i] = ap[i];
    #pragma unroll
    for (int i = 0; i < 16; i++) xr[16 + i] = xp[i];
    float pv = p[t & 63];
    float nrm = pv * pv;
    #pragma unroll
    for (int o = 32; o > 0; o >>= 1) nrm += __shfl_xor(nrm, o);
    nrm = sqrtf(nrm);
    __syncthreads();
    float4* op = (float4*)(out + (size_t)node * 64);
    float sacc = 0.f;
    #pragma unroll 1
    for (int d4 = 0; d4 < 16; d4++) {
        int d = d4 * 4;
        float a0 = 0.f, a1 = 0.f, a2 = 0.f, a3 = 0.f;
        #pragma unroll
        for (int kk = 0; kk < 32; kk++) {
            float4 xv = xr[kk];
            float4 w0 = Ush[(d+0)*32+kk], w1 = Ush[(d+1)*32+kk];
            float4 w2 = Ush[(d+2)*32+kk], w3 = Ush[(d+3)*32+kk];
            a0 = fmaf(w0.w,xv.w,fmaf(w0.z,xv.z,fmaf(w0.y,xv.y,fmaf(w0.x,xv.x,a0))));
            a1 = fmaf(w1.w,xv.w,fmaf(w1.z,xv.z,fmaf(w1.y,xv.y,fmaf(w1.x,xv.x,a1))));
            a2 = fmaf(w2.w,xv.w,fmaf(w2.z,xv.z,fmaf(w2.y,xv.y,fmaf(w2.x,xv.x,a2))));
            a3 = fmaf(w3.w,xv.w,fmaf(w3.z,xv.z,fmaf(w3.y,xv.y,fmaf(w3.x,xv.x,a3))));
        }
        a0 = fmaxf(a0, 0.f); a1 = fmaxf(a1, 0.f);
        a2 = fmaxf(a2, 0.f); a3 = fmaxf(a3, 0.f);
        sacc = fmaf(a0, p[d], fmaf(a1, p[d+1], fmaf(a2, p[d+2], fmaf(a3, p[d+3], sacc))));
        op[d4] = make_float4(a0, a1, a2, a3);
    }
    score[node] = sacc / nrm;
}

// ---------- layer-3 direct edge aggregation (float4, LDS atomics) ----------
__global__ __launch_bounds__(1024) void k_edge_max(const int2* __restrict__ edges,
                                                   const float4* __restrict__ msg4,
                                                   float4* __restrict__ aggr4,
                                                   int nper) {
    extern __shared__ unsigned smax[];   // [nper][16] dwords, xor-swizzled
    int g = blockIdx.x, q = blockIdx.y;
    int t = threadIdx.x;
    int nodebase = g * nper;
    int q4 = q * 4;
    for (int i = t; i < nper * 4; i += 1024) {
        int node = i >> 2, dd = (i & 3) * 4;
        float4 v = msg4[(size_t)(nodebase + node) * 16 + q4 + (i & 3)];
        int b0 = node << 4, sw = node & 15;
        smax[b0 | ((dd+0) ^ sw)] = __float_as_uint(v.x);
        smax[b0 | ((dd+1) ^ sw)] = __float_as_uint(v.y);
        smax[b0 | ((dd+2) ^ sw)] = __float_as_uint(v.z);
        smax[b0 | ((dd+3) ^ sw)] = __float_as_uint(v.w);
    }
    __syncthreads();
    const int2* eb = edges + g * EPG;
    int f4 = t & 3, d4 = f4 * 4, es = t >> 2;
    for (int base = 0; base < EPG; base += 1024) {
        int2 sd[4];
        float4 v[4];
        #pragma unroll
        for (int u = 0; u < 4; u++) sd[u] = eb[base + u * 256 + es];
        #pragma unroll
        for (int u = 0; u < 4; u++)
            v[u] = (sd[u].x >= 0) ? msg4[(size_t)sd[u].x * 16 + q4 + f4]
                                  : make_float4(0.f, 0.f, 0.f, 0.f);
        #pragma unroll
        for (int u = 0; u < 4; u++) {
            if (sd[u].x >= 0) {
                int ln = sd[u].y - nodebase;
                int b0 = ln << 4, sw = ln & 15;
                atomicMax(&smax[b0 | ((d4+0) ^ sw)], __float_as_uint(v[u].x));
                atomicMax(&smax[b0 | ((d4+1) ^ sw)], __float_as_uint(v[u].y));
                atomicMax(&smax[b0 | ((d4+2) ^ sw)], __float_as_uint(v[u].z));
                atomicMax(&smax[b0 | ((d4+3) ^ sw)], __float_as_uint(v[u].w));
            }
        }
    }
    __syncthreads();
    for (int i = t; i < nper * 4; i += 1024) {
        int node = i >> 2, dd = (i & 3) * 4;
        int b0 = node << 4, sw = node & 15;
        float4 v;
        v.x = __uint_as_float(smax[b0 | ((dd+0) ^ sw)]);
        v.y = __uint_as_float(smax[b0 | ((dd+1) ^ sw)]);
        v.z = __uint_as_float(smax[b0 | ((dd+2) ^ sw)]);
        v.w = __uint_as_float(smax[b0 | ((dd+3) ^ sw)]);
        aggr4[(size_t)(nodebase + node) * 16 + q4 + (i & 3)] = v;
    }
}

// ---------- topk (bitonic, desc value / asc index) + in-LDS inverse + edge remap ----------
__global__ __launch_bounds__(1024) void k_topk_remap(const float* __restrict__ score,
                                                     const int* __restrict__ combo,
                                                     const float* __restrict__ scoreT,
                                                     int nper, int k,
                                                     float* __restrict__ topv,
                                                     int* __restrict__ topi,
                                                     int2* __restrict__ edges,
                                                     int do_remap) {
    __shared__ float sv[1024];
    __shared__ int   si[1024];
    __shared__ int   invl[1024];
    int g = blockIdx.x;
    int i = threadIdx.x;
    float v = -INFINITY;
    if (i < nper) v = combo ? scoreT[combo[g * nper + i]] : score[g * nper + i];
    sv[i] = v;
    si[i] = i;
    __syncthreads();
    for (int ksz = 2; ksz <= 1024; ksz <<= 1) {
        for (int j = ksz >> 1; j > 0; j >>= 1) {
            int ixj = i ^ j;
            if (ixj > i) {
                float va = sv[i], vb = sv[ixj];
                int ia = si[i], ib = si[ixj];
                bool up = ((i & ksz) == 0);
                bool aBefore = (va > vb) || (va == vb && ia < ib);
                if (up != aBefore) { sv[i] = vb; sv[ixj] = va; si[i] = ib; si[ixj] = ia; }
            }
            __syncthreads();
        }
    }
    if (i < k) { topv[g * 1024 + i] = sv[i]; topi[g * 1024 + i] = si[i]; }
    int s = si[i];
    if (s < nper) invl[s] = (i < k) ? (g * k + i) : -1;
    __syncthreads();
    if (do_remap) {
        int2* eb = edges + g * EPG;
        int nb = g * nper;
        for (int e = i; e < EPG; e += 1024) {
            int2 sd = eb[e];
            if (sd.x < 0) continue;
            int ns = invl[sd.x - nb], nd = invl[sd.y - nb];
            eb[e] = (ns >= 0 && nd >= 0) ? make_int2(ns, nd) : make_int2(-1, sd.y);
        }
    }
}

// ---------- gathers (+ fused readout) ----------

// L1: x2[new] = x2T[combo1[sel]] (pre-scaled); writes combo2 and r1.
__global__ __launch_bounds__(1024) void k_gather1(const int* __restrict__ combo1,
                                                  const float* __restrict__ x2T,
                                                  const int* __restrict__ topi,
                                                  float* __restrict__ xnew,
                                                  int* __restrict__ combo2,
                                                  float* __restrict__ r,
                                                  int nper, int k) {
    __shared__ float smx[16][64], ssm[16][64];
    int g = blockIdx.x, t = threadIdx.x;
    int d = t & 63, c16 = t >> 6;
    float m = -INFINITY, s = 0.f;
    for (int j = c16; j < k; j += 16) {
        int src = topi[g * 1024 + j];
        int cb = combo1[g * nper + src];
        float v = x2T[cb * 64 + d];
        xnew[((size_t)g * k + j) * 64 + d] = v;
        if (d == 0) combo2[g * k + j] = cb;
        m = fmaxf(m, v); s += v;
    }
    smx[c16][d] = m; ssm[c16][d] = s;
    __syncthreads();
    if (c16 == 0) {
        #pragma unroll
        for (int u = 1; u < 16; u++) { m = fmaxf(m, smx[u][d]); s += ssm[u][d]; }
        r[g * 128 + d] = m;
        r[g * 128 + 64 + d] = s / (float)k;
    }
}

// generic: xnew[j] = x[sel]*tanh(topv[j]) + fused readout
__global__ __launch_bounds__(1024) void k_gather_readout(const float* __restrict__ x,
                                                         const float* __restrict__ topv,
                                                         const int* __restrict__ topi,
                                                         float* __restrict__ xnew,
                                                         float* __restrict__ r,
                                                         int nper, int k) {
    __shared__ float sscale[1024];
    __shared__ float smx[16][64], ssm[16][64];
    int g = blockIdx.x, t = threadIdx.x;
    if (t < k) sscale[t] = tanhf(topv[g * 1024 + t]);
    __syncthreads();
    int d = t & 63, c = t >> 6;
    float m = -INFINITY, s = 0.f;
    for (int j = c; j < k; j += 16) {
        int src = topi[g * 1024 + j];
        float v = x[((size_t)(g * nper) + src) * 64 + d] * sscale[j];
        xnew[((size_t)g * k + j) * 64 + d] = v;
        m = fmaxf(m, v); s += v;
    }
    smx[c][d] = m; ssm[c][d] = s;
    __syncthreads();
    if (c == 0) {
        #pragma unroll
        for (int u = 1; u < 16; u++) { m = fmaxf(m, smx[u][d]); s += ssm[u][d]; }
        r[g * 128 + d] = m;
        r[g * 128 + 64 + d] = s / (float)k;
    }
}

__global__ void k_mlp(const float* __restrict__ r1, const float* __restrict__ r2,
                      const float* __restrict__ r3,
                      const float* __restrict__ l1W, const float* __restrict__ l1b,
                      const float* __restrict__ l2W, const float* __restrict__ l2b,
                      const float* __restrict__ l3W, const float* __restrict__ l3b,
                      float* __restrict__ out) {
    __shared__ float h[128], h1[64], h2[64];
    int g = blockIdx.x, d = threadIdx.x;   // 64 threads
    h[d]      = r1[g*128 + d]      + r2[g*128 + d]      + r3[g*128 + d];
    h[d + 64] = r1[g*128 + 64 + d] + r2[g*128 + 64 + d] + r3[g*128 + 64 + d];
    __syncthreads();
    float a = l1b[d];
    for (int k = 0; k < 128; k++) a = fmaf(l1W[d*128 + k], h[k], a);
    h1[d] = fmaxf(a, 0.f);
    __syncthreads();
    a = l2b[d];
    for (int k = 0; k < 64; k++) a = fmaf(l2W[d*64 + k], h1[k], a);
    h2[d] = fmaxf(a, 0.f);
    __syncthreads();
    a = l3b[d];
    for (int k = 0; k < 64; k++) a = fmaf(l3W[d*64 + k], h2[k], a);
    out[g*64 + d] = 1.f / (1.f + expf(-a));
}

__global__ void k_batch(float* __restrict__ out) {
    int i = blockIdx.x * blockDim.x + threadIdx.x;
    if (i < BGRAPH * KK3) out[i] = (float)(i / KK3);
}

// ---------- launch ----------

extern "C" void kernel_launch(void* const* d_in, const int* in_sizes, int n_in,
                              void* d_out, int out_size, void* d_ws, size_t ws_size,
                              hipStream_t stream) {
    const int*   x_ids = (const int*)  d_in[0];
    const int*   eidx  = (const int*)  d_in[1];
    const float* emb   = (const float*)d_in[2];
    const float* W1 = (const float*)d_in[3];  const float* b1 = (const float*)d_in[4];
    const float* U1 = (const float*)d_in[5];  const float* p1 = (const float*)d_in[6];
    const float* W2 = (const float*)d_in[7];  const float* b2 = (const float*)d_in[8];
    const float* U2 = (const float*)d_in[9];  const float* p2 = (const float*)d_in[10];
    const float* W3 = (const float*)d_in[11]; const float* b3 = (const float*)d_in[12];
    const float* U3 = (const float*)d_in[13]; const float* p3 = (const float*)d_in[14];
    const float* l1W = (const float*)d_in[15]; const float* l1b = (const float*)d_in[16];
    const float* l2W = (const float*)d_in[17]; const float* l2b = (const float*)d_in[18];
    const float* l3W = (const float*)d_in[19]; const float* l3b = (const float*)d_in[20];

    float* ws    = (float*)d_ws;
    float* xA    = ws;                         // NTOT*64
    float* xB    = xA + (size_t)NTOT * 64;
    float* xC    = xB + (size_t)NTOT * 64;
    float* score = xC + (size_t)NTOT * 64;     // NTOT
    float* topv  = score + NTOT;               // 128*1024
    float* r1    = topv + BGRAPH * 1024;
    float* r2    = r1 + BGRAPH * 128;
    float* r3    = r2 + BGRAPH * 128;
    float* msgT  = r3 + BGRAPH * 128;          // 256
    float* s1T   = msgT + 256;                 // 64
    float* x2T   = s1T + 64;                   // 4096
    float* msg2T = x2T + 4096;                 // 4096
    int2*  edges = (int2*)(msg2T + 4096);      // ETOT
    int*   topi  = (int*)(edges + ETOT);       // 128*1024
    int*   combo1= topi + BGRAPH * 1024;       // NTOT
    int*   combo2= combo1 + NTOT;              // BGRAPH*KK1
    unsigned* gmask1 = (unsigned*)(combo2 + NTOT);  // NTOT
    unsigned* m2     = gmask1 + NTOT;          // 2*BGRAPH*KK1

    const int n2 = BGRAPH * KK1;   // 104960
    const int n3 = BGRAPH * KK2;   // 83968

    // ---- layer 1 (combo space) ----
    k_copy_edges<<<(ETOT + 255) / 256, 256, 0, stream>>>(eidx, edges);
    k_zero<<<(NTOT + 255) / 256, 256, 0, stream>>>(gmask1, NTOT);
    k_msg1_table<<<4, 64, 0, stream>>>(emb, W1, b1, msgT);
    k_combo1_table<<<64, 64, 0, stream>>>(msgT, emb, U1, p1, s1T, x2T);
    k_mask1<<<(ETOT + 255) / 256, 256, 0, stream>>>(eidx, x_ids, gmask1);
    k_combo1<<<(NTOT + 255) / 256, 256, 0, stream>>>(gmask1, x_ids, combo1);
    k_topk_remap<<<BGRAPH, 1024, 0, stream>>>(nullptr, combo1, s1T, NPER0, KK1,
                                              topv, topi, edges, 1);
    k_gather1<<<BGRAPH, 1024, 0, stream>>>(combo1, x2T, topi, xA, combo2, r1, NPER0, KK1);

    // ---- layer 2 (mask aggregation + real dense) ----
    k_msg2_table<<<64, 64, 0, stream>>>(x2T, W2, b2, msg2T);
    k_mask2_init<<<(n2 + 255) / 256, 256, 0, stream>>>(combo2, m2, n2);
    k_mask2_edge<<<(ETOT + 255) / 256, 256, 0, stream>>>(edges, combo2, m2);
    k_aggr2<<<(n2 * 16 + 255) / 256, 256, 0, stream>>>(m2, (const float4*)msg2T,
                                                       (float4*)xC, n2);
    k_dense128cat<<<n2 / 128, 128, 0, stream>>>(xC, xA, U2, p2, xB, score);
    k_topk_remap<<<BGRAPH, 1024, 0, stream>>>(score, nullptr, nullptr, KK1, KK2,
                                              topv, topi, edges, 1);
    k_gather_readout<<<BGRAPH, 1024, 0, stream>>>(xB, topv, topi, xC, r2, KK1, KK2);

    // ---- layer 3 (real) ----
    k_dense64<<<n3 / 128, 128, 0, stream>>>(xC, W3, b3, xB);
    k_edge_max<<<dim3(BGRAPH, 4), 1024, KK2 * 16 * sizeof(float), stream>>>(
        edges, (const float4*)xB, (float4*)xA, KK2);
    k_dense128cat<<<n3 / 128, 128, 0, stream>>>(xA, xC, U3, p3, xB, score);
    k_topk_remap<<<BGRAPH, 1024, 0, stream>>>(score, nullptr, nullptr, KK2, KK3,
                                              topv, topi, edges, 0);
    k_gather_readout<<<BGRAPH, 1024, 0, stream>>>(xB, topv, topi, xA, r3, KK2, KK3);

    k_mlp<<<BGRAPH, 64, 0, stream>>>(r1, r2, r3, l1W, l1b, l2W, l2b, l3W, l3b, (float*)d_out);
    k_batch<<<(BGRAPH * KK3 + 255) / 256, 256, 0, stream>>>((float*)d_out + BGRAPH * DDIM);
}

// Round 10
// 401.769 us; speedup vs baseline: 8.0647x; 1.3570x over previous
//
#include <hip/hip_runtime.h>
#include <hip/hip_bf16.h>
#include <math.h>

#define BGRAPH 128
#define NPER0 1024
#define DDIM 64
#define NTOT (BGRAPH*NPER0)      // 131072
#define ETOT (NTOT*16)           // 2097152
#define EPG  (ETOT/BGRAPH)       // 16384
#define KK1 820
#define KK2 656
#define KK3 525

__device__ __forceinline__ bool cmp_before(float va, int ia, float vb, int ib) {
    return (va > vb) || (va == vb && ia < ib);
}

// ---------- layer-1 tables ----------
__global__ void k_msg1_table(const float* __restrict__ emb, const float* __restrict__ W,
                             const float* __restrict__ b, float* __restrict__ msgT) {
    int id = blockIdx.x, d = threadIdx.x;
    float a = b[d];
    for (int k = 0; k < 64; k++) a = fmaf(emb[id * 64 + k], W[d * 64 + k], a);
    msgT[id * 64 + d] = fmaxf(a, 0.f);
}

__global__ void k_combo1_table(const float* __restrict__ msgT, const float* __restrict__ emb,
                               const float* __restrict__ U, const float* __restrict__ p,
                               float* __restrict__ s1T, float* __restrict__ x2T) {
    __shared__ float cat[128];
    int c = blockIdx.x, d = threadIdx.x;
    int mask = c >> 2, id = c & 3;
    float ag = -INFINITY;
    for (int i = 0; i < 4; i++) if (mask & (1 << i)) ag = fmaxf(ag, msgT[i * 64 + d]);
    if (mask == 0) ag = 0.f;
    cat[d] = ag; cat[64 + d] = emb[id * 64 + d];
    __syncthreads();
    float a = 0.f;
    for (int k = 0; k < 128; k++) a = fmaf(U[d * 128 + k], cat[k], a);
    a = fmaxf(a, 0.f);
    float pv = p[d];
    float nrm = pv * pv, sv = a * pv;
    #pragma unroll
    for (int o = 32; o > 0; o >>= 1) { nrm += __shfl_xor(nrm, o); sv += __shfl_xor(sv, o); }
    float sc = sv / sqrtf(nrm);
    if (d == 0) s1T[c] = sc;
    x2T[c * 64 + d] = a * tanhf(sc);
}

__global__ void k_msg2_table(const float* __restrict__ x2T, const float* __restrict__ W,
                             const float* __restrict__ b, float* __restrict__ msg2T) {
    int c = blockIdx.x, d = threadIdx.x;
    float a = b[d];
    for (int k = 0; k < 64; k++) a = fmaf(x2T[c * 64 + k], W[d * 64 + k], a);
    msg2T[c * 64 + d] = fmaxf(a, 0.f);
}

// ---------- L1 fused: per-graph LDS mask -> combo + score ----------
__global__ __launch_bounds__(1024) void k_mask_combo1(const int* __restrict__ eidx,
                                                      const int* __restrict__ ids,
                                                      const float* __restrict__ s1T,
                                                      int* __restrict__ combo1,
                                                      float* __restrict__ score) {
    __shared__ unsigned lmask[1024];
    __shared__ int lids[1024];
    int g = blockIdx.x, t = threadIdx.x;
    int nb = g * NPER0;
    lids[t] = ids[nb + t];
    lmask[t] = 0u;
    __syncthreads();
    const int* es = eidx + (size_t)g * EPG;
    const int* ed = eidx + ETOT + (size_t)g * EPG;
    for (int e = t; e < EPG; e += 1024)
        atomicOr(&lmask[ed[e] - nb], 1u << lids[es[e] - nb]);
    __syncthreads();
    int id = lids[t];
    int cb = (int)(((lmask[t] | (1u << id)) << 2) | (unsigned)id);
    combo1[nb + t] = cb;
    score[nb + t] = s1T[cb];
}

// ---------- topk: hybrid shuffle/LDS bitonic + inverse perm + edge compaction ----------
// mode 0: compact from raw eidx (int src/dst); mode 1: compact from ushort2 list;
// mode 2: sort only.
__global__ __launch_bounds__(1024) void k_topk(const float* __restrict__ score,
                                               int nper, int k,
                                               float* __restrict__ topv,
                                               int* __restrict__ topi,
                                               const int* __restrict__ rawsrc,
                                               const int* __restrict__ rawdst,
                                               const ushort2* __restrict__ ein2,
                                               const int* __restrict__ ecnt_in,
                                               ushort2* __restrict__ eout,
                                               int* __restrict__ ecnt_out,
                                               int mode) {
    __shared__ float sv[1024];
    __shared__ int   si[1024];
    __shared__ int   invl[1024];
    __shared__ int   scnt;
    int g = blockIdx.x, i = threadIdx.x;
    if (i == 0) scnt = 0;
    sv[i] = (i < nper) ? score[g * nper + i] : -INFINITY;
    si[i] = i;
    __syncthreads();
    float v = sv[i]; int ix = si[i];
    // stages ksz=2..64 fully intra-wave
    #pragma unroll
    for (int ksz = 2; ksz <= 64; ksz <<= 1) {
        bool up = (i & ksz) == 0;
        for (int j = ksz >> 1; j > 0; j >>= 1) {
            float ov = __shfl_xor(v, j);
            int   oi = __shfl_xor(ix, j);
            bool take = cmp_before(v, ix, ov, oi) ^ ((i & j) != 0) ^ (!up);
            if (!take) { v = ov; ix = oi; }
        }
    }
    sv[i] = v; si[i] = ix;
    __syncthreads();
    for (int ksz = 128; ksz <= 1024; ksz <<= 1) {
        bool up = (i & ksz) == 0;
        for (int j = ksz >> 1; j >= 64; j >>= 1) {
            int ixj = i ^ j;
            if (ixj > i) {
                float va = sv[i], vb = sv[ixj];
                int ia = si[i], ib = si[ixj];
                if (up != cmp_before(va, ia, vb, ib)) {
                    sv[i] = vb; sv[ixj] = va; si[i] = ib; si[ixj] = ia;
                }
            }
            __syncthreads();
        }
        v = sv[i]; ix = si[i];
        for (int j = 32; j > 0; j >>= 1) {
            float ov = __shfl_xor(v, j);
            int   oi = __shfl_xor(ix, j);
            bool take = cmp_before(v, ix, ov, oi) ^ ((i & j) != 0) ^ (!up);
            if (!take) { v = ov; ix = oi; }
        }
        sv[i] = v; si[i] = ix;
        __syncthreads();
    }
    if (i < k) { topv[g * 1024 + i] = sv[i]; topi[g * 1024 + i] = si[i]; }
    int s = si[i];
    if (s < nper) invl[s] = (i < k) ? i : -1;   // LOCAL new index
    if (mode == 2) return;
    __syncthreads();
    int pcin = (mode == 0) ? EPG : ecnt_in[g];
    for (int e = i; e < pcin; e += 1024) {
        int ns, nd;
        if (mode == 0) {
            ns = invl[rawsrc[(size_t)g * EPG + e] - g * nper];
            nd = invl[rawdst[(size_t)g * EPG + e] - g * nper];
        } else {
            ushort2 sd = ein2[(size_t)g * EPG + e];
            if (sd.x == 0xFFFFu) continue;
            ns = invl[sd.x]; nd = invl[sd.y];
        }
        if (ns >= 0 && nd >= 0) {
            int pos = atomicAdd(&scnt, 1);
            eout[(size_t)g * EPG + pos] = make_ushort2((unsigned short)ns, (unsigned short)nd);
        }
    }
    __syncthreads();
    int cnt = scnt;
    int pc = (cnt + 1023) & ~1023;
    for (int e2 = cnt + i; e2 < pc; e2 += 1024)
        eout[(size_t)g * EPG + e2] = make_ushort2(0xFFFFu, 0);
    if (i == 0) ecnt_out[g] = pc;
}

// ---------- L2 fused: per-graph LDS 64-bit mask aggregation -> aggr ----------
__global__ __launch_bounds__(1024) void k_mask_aggr2(const ushort2* __restrict__ edges,
                                                     const int* __restrict__ ecnt,
                                                     const int* __restrict__ combo2,
                                                     const float4* __restrict__ msg2T4,
                                                     float4* __restrict__ aggr4) {
    __shared__ float4 tab[1024];          // 64 x 16 f4 = 16 KB
    __shared__ unsigned mlo[KK1], mhi[KK1];
    __shared__ int lcombo[KK1];
    int g = blockIdx.x, t = threadIdx.x;
    tab[t] = msg2T4[t];
    for (int i2 = t; i2 < KK1; i2 += 1024) {
        int c = combo2[g * KK1 + i2];
        lcombo[i2] = c;
        mlo[i2] = (c < 32) ? (1u << c) : 0u;
        mhi[i2] = (c < 32) ? 0u : (1u << (c - 32));
    }
    __syncthreads();
    const ushort2* eb = edges + (size_t)g * EPG;
    int pc = ecnt[g];
    for (int e = t; e < pc; e += 1024) {
        ushort2 sd = eb[e];
        if (sd.x != 0xFFFFu) {
            int c = lcombo[sd.x];
            if (c < 32) atomicOr(&mlo[sd.y], 1u << c);
            else        atomicOr(&mhi[sd.y], 1u << (c - 32));
        }
    }
    __syncthreads();
    for (int i2 = t; i2 < KK1 * 16; i2 += 1024) {
        int node = i2 >> 4, f = i2 & 15;
        unsigned lo = mlo[node], hi = mhi[node];
        float4 a = make_float4(-INFINITY, -INFINITY, -INFINITY, -INFINITY);
        while (lo) {
            int bb = __ffs(lo) - 1; lo &= lo - 1;
            float4 w = tab[bb * 16 + f];
            a.x = fmaxf(a.x, w.x); a.y = fmaxf(a.y, w.y);
            a.z = fmaxf(a.z, w.z); a.w = fmaxf(a.w, w.w);
        }
        while (hi) {
            int bb = __ffs(hi) - 1; hi &= hi - 1;
            float4 w = tab[(32 + bb) * 16 + f];
            a.x = fmaxf(a.x, w.x); a.y = fmaxf(a.y, w.y);
            a.z = fmaxf(a.z, w.z); a.w = fmaxf(a.w, w.w);
        }
        aggr4[((size_t)g * KK1 + node) * 16 + f] = a;
    }
}

// ---------- dense kernels (weights in LDS) ----------
__global__ __launch_bounds__(128) void k_dense64(const float* __restrict__ x,
                                                 const float* __restrict__ W,
                                                 const float* __restrict__ b,
                                                 float* __restrict__ out) {
    __shared__ float4 Wsh[64 * 16];
    int t = threadIdx.x;
    const float4* W4 = (const float4*)W;
    #pragma unroll
    for (int i = 0; i < 8; i++) Wsh[t + i * 128] = W4[t + i * 128];
    int node = blockIdx.x * 128 + t;
    float4 xr[16];
    const float4* xp = (const float4*)(x + (size_t)node * 64);
    #pragma unroll
    for (int i = 0; i < 16; i++) xr[i] = xp[i];
    __syncthreads();
    float4* op = (float4*)(out + (size_t)node * 64);
    #pragma unroll 1
    for (int d4 = 0; d4 < 16; d4++) {
        int d = d4 * 4;
        float a0 = b[d], a1 = b[d+1], a2 = b[d+2], a3 = b[d+3];
        #pragma unroll
        for (int kk = 0; kk < 16; kk++) {
            float4 xv = xr[kk];
            float4 w0 = Wsh[(d+0)*16+kk], w1 = Wsh[(d+1)*16+kk];
            float4 w2 = Wsh[(d+2)*16+kk], w3 = Wsh[(d+3)*16+kk];
            a0 = fmaf(w0.w,xv.w,fmaf(w0.z,xv.z,fmaf(w0.y,xv.y,fmaf(w0.x,xv.x,a0))));
            a1 = fmaf(w1.w,xv.w,fmaf(w1.z,xv.z,fmaf(w1.y,xv.y,fmaf(w1.x,xv.x,a1))));
            a2 = fmaf(w2.w,xv.w,fmaf(w2.z,xv.z,fmaf(w2.y,xv.y,fmaf(w2.x,xv.x,a2))));
            a3 = fmaf(w3.w,xv.w,fmaf(w3.z,xv.z,fmaf(w3.y,xv.y,fmaf(w3.x,xv.x,a3))));
        }
        op[d4] = make_float4(fmaxf(a0,0.f), fmaxf(a1,0.f), fmaxf(a2,0.f), fmaxf(a3,0.f));
    }
}

__global__ __launch_bounds__(128) void k_dense128cat(const float* __restrict__ aggr,
                                                     const float* __restrict__ x,
                                                     const float* __restrict__ U,
                                                     const float* __restrict__ p,
                                                     float* __restrict__ out,
                                                     float* __restrict__ score) {
    __shared__ float4 Ush[64 * 32];
    int t = threadIdx.x;
    const float4* U4 = (const float4*)U;
    #pragma unroll
    for (int i = 0; i < 16; i++) Ush[t + i * 128] = U4[t + i * 128];
    int node = blockIdx.x * 128 + t;
    float4 xr[32];
    const float4* ap = (const float4*)(aggr + (size_t)node * 64);
    const float4* xp = (const float4*)(x    + (size_t)node * 64);
    #pragma unroll
    for (int i = 0; i < 16; i++) xr[i] = ap[i];
    #pragma unroll
    for (int i = 0; i < 16; i++) xr[16 + i] = xp[i];
    float pv = p[t & 63];
    float nrm = pv * pv;
    #pragma unroll
    for (int o = 32; o > 0; o >>= 1) nrm += __shfl_xor(nrm, o);
    nrm = sqrtf(nrm);
    __syncthreads();
    float4* op = (float4*)(out + (size_t)node * 64);
    float sacc = 0.f;
    #pragma unroll 1
    for (int d4 = 0; d4 < 16; d4++) {
        int d = d4 * 4;
        float a0 = 0.f, a1 = 0.f, a2 = 0.f, a3 = 0.f;
        #pragma unroll
        for (int kk = 0; kk < 32; kk++) {
            float4 xv = xr[kk];
            float4 w0 = Ush[(d+0)*32+kk], w1 = Ush[(d+1)*32+kk];
            float4 w2 = Ush[(d+2)*32+kk], w3 = Ush[(d+3)*32+kk];
            a0 = fmaf(w0.w,xv.w,fmaf(w0.z,xv.z,fmaf(w0.y,xv.y,fmaf(w0.x,xv.x,a0))));
            a1 = fmaf(w1.w,xv.w,fmaf(w1.z,xv.z,fmaf(w1.y,xv.y,fmaf(w1.x,xv.x,a1))));
            a2 = fmaf(w2.w,xv.w,fmaf(w2.z,xv.z,fmaf(w2.y,xv.y,fmaf(w2.x,xv.x,a2))));
            a3 = fmaf(w3.w,xv.w,fmaf(w3.z,xv.z,fmaf(w3.y,xv.y,fmaf(w3.x,xv.x,a3))));
        }
        a0 = fmaxf(a0, 0.f); a1 = fmaxf(a1, 0.f);
        a2 = fmaxf(a2, 0.f); a3 = fmaxf(a3, 0.f);
        sacc = fmaf(a0, p[d], fmaf(a1, p[d+1], fmaf(a2, p[d+2], fmaf(a3, p[d+3], sacc))));
        op[d4] = make_float4(a0, a1, a2, a3);
    }
    score[node] = sacc / nrm;
}

// ---------- L3 edge aggregation (compacted ushort2 edges, LDS atomics) ----------
__global__ __launch_bounds__(1024) void k_edge_max(const ushort2* __restrict__ edges,
                                                   const int* __restrict__ ecnt,
                                                   const float4* __restrict__ msg4,
                                                   float4* __restrict__ aggr4,
                                                   int nper) {
    extern __shared__ unsigned smax[];
    int g = blockIdx.x, q = blockIdx.y, t = threadIdx.x;
    int nodebase = g * nper;
    int q4 = q * 4;
    for (int i = t; i < nper * 4; i += 1024) {
        int node = i >> 2, dd = (i & 3) * 4;
        float4 vv = msg4[(size_t)(nodebase + node) * 16 + q4 + (i & 3)];
        int b0 = node << 4, sw = node & 15;
        smax[b0 | ((dd+0) ^ sw)] = __float_as_uint(vv.x);
        smax[b0 | ((dd+1) ^ sw)] = __float_as_uint(vv.y);
        smax[b0 | ((dd+2) ^ sw)] = __float_as_uint(vv.z);
        smax[b0 | ((dd+3) ^ sw)] = __float_as_uint(vv.w);
    }
    __syncthreads();
    const ushort2* eb = edges + (size_t)g * EPG;
    int pc = ecnt[g];
    int f4 = t & 3, d4 = f4 * 4, es = t >> 2;
    for (int base = 0; base < pc; base += 1024) {
        ushort2 sd[4];
        float4 vv[4];
        #pragma unroll
        for (int u = 0; u < 4; u++) sd[u] = eb[base + u * 256 + es];
        #pragma unroll
        for (int u = 0; u < 4; u++)
            vv[u] = (sd[u].x != 0xFFFFu)
                  ? msg4[(size_t)(nodebase + sd[u].x) * 16 + q4 + f4]
                  : make_float4(0.f, 0.f, 0.f, 0.f);
        #pragma unroll
        for (int u = 0; u < 4; u++) {
            if (sd[u].x != 0xFFFFu) {
                int ln = sd[u].y;
                int b0 = ln << 4, sw = ln & 15;
                atomicMax(&smax[b0 | ((d4+0) ^ sw)], __float_as_uint(vv[u].x));
                atomicMax(&smax[b0 | ((d4+1) ^ sw)], __float_as_uint(vv[u].y));
                atomicMax(&smax[b0 | ((d4+2) ^ sw)], __float_as_uint(vv[u].z));
                atomicMax(&smax[b0 | ((d4+3) ^ sw)], __float_as_uint(vv[u].w));
            }
        }
    }
    __syncthreads();
    for (int i = t; i < nper * 4; i += 1024) {
        int node = i >> 2, dd = (i & 3) * 4;
        int b0 = node << 4, sw = node & 15;
        float4 vv;
        vv.x = __uint_as_float(smax[b0 | ((dd+0) ^ sw)]);
        vv.y = __uint_as_float(smax[b0 | ((dd+1) ^ sw)]);
        vv.z = __uint_as_float(smax[b0 | ((dd+2) ^ sw)]);
        vv.w = __uint_as_float(smax[b0 | ((dd+3) ^ sw)]);
        aggr4[(size_t)(nodebase + node) * 16 + q4 + (i & 3)] = vv;
    }
}

// ---------- gathers (+ fused readout) ----------
__global__ __launch_bounds__(1024) void k_gather1(const int* __restrict__ combo1,
                                                  const float* __restrict__ x2T,
                                                  const int* __restrict__ topi,
                                                  float* __restrict__ xnew,
                                                  int* __restrict__ combo2,
                                                  float* __restrict__ r,
                                                  int nper, int k) {
    __shared__ float smx[16][64], ssm[16][64];
    int g = blockIdx.x, t = threadIdx.x;
    int d = t & 63, c16 = t >> 6;
    float m = -INFINITY, s = 0.f;
    for (int j = c16; j < k; j += 16) {
        int src = topi[g * 1024 + j];
        int cb = combo1[g * nper + src];
        float v = x2T[cb * 64 + d];
        xnew[((size_t)g * k + j) * 64 + d] = v;
        if (d == 0) combo2[g * k + j] = cb;
        m = fmaxf(m, v); s += v;
    }
    smx[c16][d] = m; ssm[c16][d] = s;
    __syncthreads();
    if (c16 == 0) {
        #pragma unroll
        for (int u = 1; u < 16; u++) { m = fmaxf(m, smx[u][d]); s += ssm[u][d]; }
        r[g * 128 + d] = m;
        r[g * 128 + 64 + d] = s / (float)k;
    }
}

__global__ __launch_bounds__(1024) void k_gather_readout(const float* __restrict__ x,
                                                         const float* __restrict__ topv,
                                                         const int* __restrict__ topi,
                                                         float* __restrict__ xnew,
                                                         float* __restrict__ r,
                                                         int nper, int k) {
    __shared__ float sscale[1024];
    __shared__ float smx[16][64], ssm[16][64];
    int g = blockIdx.x, t = threadIdx.x;
    if (t < k) sscale[t] = tanhf(topv[g * 1024 + t]);
    __syncthreads();
    int d = t & 63, c = t >> 6;
    float m = -INFINITY, s = 0.f;
    for (int j = c; j < k; j += 16) {
        int src = topi[g * 1024 + j];
        float v = x[((size_t)(g * nper) + src) * 64 + d] * sscale[j];
        xnew[((size_t)g * k + j) * 64 + d] = v;
        m = fmaxf(m, v); s += v;
    }
    smx[c][d] = m; ssm[c][d] = s;
    __syncthreads();
    if (c == 0) {
        #pragma unroll
        for (int u = 1; u < 16; u++) { m = fmaxf(m, smx[u][d]); s += ssm[u][d]; }
        r[g * 128 + d] = m;
        r[g * 128 + 64 + d] = s / (float)k;
    }
}

__global__ void k_mlp(const float* __restrict__ r1, const float* __restrict__ r2,
                      const float* __restrict__ r3,
                      const float* __restrict__ l1W, const float* __restrict__ l1b,
                      const float* __restrict__ l2W, const float* __restrict__ l2b,
                      const float* __restrict__ l3W, const float* __restrict__ l3b,
                      float* __restrict__ out) {
    __shared__ float h[128], h1[64], h2[64];
    int g = blockIdx.x, d = threadIdx.x;
    h[d]      = r1[g*128 + d]      + r2[g*128 + d]      + r3[g*128 + d];
    h[d + 64] = r1[g*128 + 64 + d] + r2[g*128 + 64 + d] + r3[g*128 + 64 + d];
    __syncthreads();
    float a = l1b[d];
    for (int k = 0; k < 128; k++) a = fmaf(l1W[d*128 + k], h[k], a);
    h1[d] = fmaxf(a, 0.f);
    __syncthreads();
    a = l2b[d];
    for (int k = 0; k < 64; k++) a = fmaf(l2W[d*64 + k], h1[k], a);
    h2[d] = fmaxf(a, 0.f);
    __syncthreads();
    a = l3b[d];
    for (int k = 0; k < 64; k++) a = fmaf(l3W[d*64 + k], h2[k], a);
    out[g*64 + d] = 1.f / (1.f + expf(-a));
}

__global__ void k_batch(float* __restrict__ out) {
    int i = blockIdx.x * blockDim.x + threadIdx.x;
    if (i < BGRAPH * KK3) out[i] = (float)(i / KK3);
}

// ---------- launch ----------
extern "C" void kernel_launch(void* const* d_in, const int* in_sizes, int n_in,
                              void* d_out, int out_size, void* d_ws, size_t ws_size,
                              hipStream_t stream) {
    const int*   x_ids = (const int*)  d_in[0];
    const int*   eidx  = (const int*)  d_in[1];
    const float* emb   = (const float*)d_in[2];
    const float* W1 = (const float*)d_in[3];  const float* b1 = (const float*)d_in[4];
    const float* U1 = (const float*)d_in[5];  const float* p1 = (const float*)d_in[6];
    const float* W2 = (const float*)d_in[7];  const float* b2 = (const float*)d_in[8];
    const float* U2 = (const float*)d_in[9];  const float* p2 = (const float*)d_in[10];
    const float* W3 = (const float*)d_in[11]; const float* b3 = (const float*)d_in[12];
    const float* U3 = (const float*)d_in[13]; const float* p3 = (const float*)d_in[14];
    const float* l1W = (const float*)d_in[15]; const float* l1b = (const float*)d_in[16];
    const float* l2W = (const float*)d_in[17]; const float* l2b = (const float*)d_in[18];
    const float* l3W = (const float*)d_in[19]; const float* l3b = (const float*)d_in[20];

    float* ws    = (float*)d_ws;
    float* xA    = ws;
    float* xB    = xA + (size_t)NTOT * 64;
    float* xC    = xB + (size_t)NTOT * 64;
    float* score = xC + (size_t)NTOT * 64;
    float* topv  = score + NTOT;
    float* r1    = topv + BGRAPH * 1024;
    float* r2    = r1 + BGRAPH * 128;
    float* r3    = r2 + BGRAPH * 128;
    float* msgT  = r3 + BGRAPH * 128;          // 256
    float* s1T   = msgT + 256;                 // 64
    float* x2T   = s1T + 64;                   // 4096
    float* msg2T = x2T + 4096;                 // 4096
    ushort2* edgesB = (ushort2*)(msg2T + 4096);   // ETOT
    ushort2* edgesA = edgesB + ETOT;              // ETOT
    int* topi   = (int*)(edgesA + ETOT);          // 128*1024
    int* combo1 = topi + BGRAPH * 1024;           // NTOT
    int* combo2 = combo1 + NTOT;                  // BGRAPH*KK1
    int* ecnt1  = combo2 + BGRAPH * KK1;          // 128
    int* ecnt2  = ecnt1 + BGRAPH;                 // 128

    const int n2 = BGRAPH * KK1;   // 104960
    const int n3 = BGRAPH * KK2;   // 83968

    // ---- layer 1 (combo space, all-LDS mask) ----
    k_msg1_table<<<4, 64, 0, stream>>>(emb, W1, b1, msgT);
    k_combo1_table<<<64, 64, 0, stream>>>(msgT, emb, U1, p1, s1T, x2T);
    k_msg2_table<<<64, 64, 0, stream>>>(x2T, W2, b2, msg2T);
    k_mask_combo1<<<BGRAPH, 1024, 0, stream>>>(eidx, x_ids, s1T, combo1, score);
    k_topk<<<BGRAPH, 1024, 0, stream>>>(score, NPER0, KK1, topv, topi,
                                        eidx, eidx + ETOT, nullptr, nullptr,
                                        edgesB, ecnt1, 0);
    k_gather1<<<BGRAPH, 1024, 0, stream>>>(combo1, x2T, topi, xA, combo2, r1, NPER0, KK1);

    // ---- layer 2 (LDS 64-bit mask aggregation + real dense) ----
    k_mask_aggr2<<<BGRAPH, 1024, 0, stream>>>(edgesB, ecnt1, combo2,
                                              (const float4*)msg2T, (float4*)xC);
    k_dense128cat<<<n2 / 128, 128, 0, stream>>>(xC, xA, U2, p2, xB, score);
    k_topk<<<BGRAPH, 1024, 0, stream>>>(score, KK1, KK2, topv, topi,
                                        nullptr, nullptr, edgesB, ecnt1,
                                        edgesA, ecnt2, 1);
    k_gather_readout<<<BGRAPH, 1024, 0, stream>>>(xB, topv, topi, xC, r2, KK1, KK2);

    // ---- layer 3 (real) ----
    k_dense64<<<n3 / 128, 128, 0, stream>>>(xC, W3, b3, xB);
    k_edge_max<<<dim3(BGRAPH, 4), 1024, KK2 * 16 * sizeof(float), stream>>>(
        edgesA, ecnt2, (const float4*)xB, (float4*)xA, KK2);
    k_dense128cat<<<n3 / 128, 128, 0, stream>>>(xA, xC, U3, p3, xB, score);
    k_topk<<<BGRAPH, 1024, 0, stream>>>(score, KK2, KK3, topv, topi,
                                        nullptr, nullptr, nullptr, nullptr,
                                        nullptr, nullptr, 2);
    k_gather_readout<<<BGRAPH, 1024, 0, stream>>>(xB, topv, topi, xA, r3, KK2, KK3);

    k_mlp<<<BGRAPH, 64, 0, stream>>>(r1, r2, r3, l1W, l1b, l2W, l2b, l3W, l3b, (float*)d_out);
    k_batch<<<(BGRAPH * KK3 + 255) / 256, 256, 0, stream>>>((float*)d_out + BGRAPH * DDIM);
}